// Round 7
// baseline (462.046 us; speedup 1.0000x reference)
//
#include <hip/hip_runtime.h>

typedef __attribute__((ext_vector_type(8))) short s16x8;
typedef __attribute__((ext_vector_type(4))) short s16x4;
typedef __attribute__((ext_vector_type(4))) float f32x4;

static __device__ __forceinline__ short f2bf(float f) {
    unsigned u = __builtin_bit_cast(unsigned, f);
    u = (u + 0x7FFFu + ((u >> 16) & 1u)) >> 16;
    return (short)u;
}

__device__ __forceinline__ void gload16(const short* g, short* l) {
    __builtin_amdgcn_global_load_lds(
        (const __attribute__((address_space(1))) void*)g,
        (__attribute__((address_space(3))) void*)l,
        16, 0, 0);
}

// ---------------- transpose + fp32->bf16 convert:  W[K][N] f32 -> Wt[N][K] bf16
__global__ __launch_bounds__(256) void transpose_convert(
    const float* __restrict__ W, short* __restrict__ Wt, int K, int N)
{
    __shared__ float tile[32][33];
    const int bx = blockIdx.x * 32;  // N
    const int by = blockIdx.y * 32;  // K
    const int tx = threadIdx.x;      // 0..31
    const int ty = threadIdx.y;      // 0..7
    for (int i = 0; i < 32; i += 8)
        tile[ty + i][tx] = W[(size_t)(by + ty + i) * N + bx + tx];
    __syncthreads();
    for (int i = 0; i < 32; i += 8)
        Wt[(size_t)(bx + ty + i) * K + by + tx] = f2bf(tile[tx][ty + i]);
}

// ---------------- V transpose: qkv V-part [8][1024][12][64] -> vT[96][64][1024] bf16
__global__ __launch_bounds__(256) void transpose_v(
    const short* __restrict__ qkv, short* __restrict__ vT)
{
    __shared__ short tile[32][68];
    const int nt = blockIdx.x;   // 0..31
    const int bh = blockIdx.y;   // 0..95
    const int b = bh / 12, h = bh % 12;
    const int t = threadIdx.x;
    {
        const int ty = t >> 3, tx = t & 7;
        *(s16x8*)&tile[ty][tx * 8] =
            *(const s16x8*)(qkv + ((size_t)(b * 1024 + nt * 32 + ty)) * 2304 + 1536 + h * 64 + tx * 8);
    }
    __syncthreads();
    {
        const int d = t >> 2, tx = t & 3;
        s16x8 v;
#pragma unroll
        for (int i = 0; i < 8; i++) v[i] = tile[tx * 8 + i][d];
        *(s16x8*)(vT + ((size_t)(bh * 64 + d)) * 1024 + nt * 32 + tx * 8) = v;
    }
}

// ---------------- LayerNorm: x[8192][768] f32 -> out bf16
__global__ __launch_bounds__(256) void layernorm_kernel(
    const float* __restrict__ x, const float* __restrict__ g,
    const float* __restrict__ b, short* __restrict__ out)
{
    const int row = blockIdx.x;
    const float* xr = x + (size_t)row * 768;
    const int t = threadIdx.x;
    float v0 = xr[t], v1 = xr[t + 256], v2 = xr[t + 512];
    __shared__ float red[4];

    float s = v0 + v1 + v2;
    for (int off = 32; off >= 1; off >>= 1) s += __shfl_down(s, off, 64);
    if ((t & 63) == 0) red[t >> 6] = s;
    __syncthreads();
    const float mean = (red[0] + red[1] + red[2] + red[3]) * (1.0f / 768.0f);
    const float d0 = v0 - mean, d1 = v1 - mean, d2 = v2 - mean;
    __syncthreads();
    float ss = d0 * d0 + d1 * d1 + d2 * d2;
    for (int off = 32; off >= 1; off >>= 1) ss += __shfl_down(ss, off, 64);
    if ((t & 63) == 0) red[t >> 6] = ss;
    __syncthreads();
    const float var = (red[0] + red[1] + red[2] + red[3]) * (1.0f / 768.0f);
    const float rstd = rsqrtf(var + 1e-5f);
    out[(size_t)row * 768 + t]       = f2bf(d0 * rstd * g[t] + b[t]);
    out[(size_t)row * 768 + t + 256] = f2bf(d1 * rstd * g[t + 256] + b[t + 256]);
    out[(size_t)row * 768 + t + 512] = f2bf(d2 * rstd * g[t + 512] + b[t + 512]);
}

// ---------------- GEMM (m97 structure, single-buffered): C = A * Bt^T + bias
template <int MODE>
__global__ __launch_bounds__(256) void gemm_bt(
    const short* __restrict__ A, const short* __restrict__ Bt,
    const float* __restrict__ bias, const float* __restrict__ res,
    void* __restrict__ out, int M, int N, int K)
{
    __shared__ __align__(16) short As[128 * 32];
    __shared__ __align__(16) short Bs[128 * 32];

    const int t = threadIdx.x;
    const int l = t & 63;
    const int w = t >> 6;
    const int wr = (w >> 1) * 64;
    const int wc = (w & 1) * 64;
    const int tm = blockIdx.y * 128;
    const int tn = blockIdx.x * 128;

    const int lrow = l >> 2;
    const int lcol = (l & 3) * 8;
    const int ca = w * 2;
    const short* aS0 = A  + (size_t)(tm + ca * 16 + lrow) * K + lcol;
    const short* aS1 = aS0 + (size_t)16 * K;
    const short* bS0 = Bt + (size_t)(tn + ca * 16 + lrow) * K + lcol;
    const short* bS1 = bS0 + (size_t)16 * K;
    short* lA0 = &As[ca * 512];
    short* lA1 = &As[ca * 512 + 512];
    short* lB0 = &Bs[ca * 512];
    short* lB1 = &Bs[ca * 512 + 512];

    const int fr = l & 15;
    const int kq = (l >> 4) * 8;

    f32x4 acc[4][4] = {};

    for (int k0 = 0; k0 < K; k0 += 32) {
        gload16(aS0 + k0, lA0);
        gload16(aS1 + k0, lA1);
        gload16(bS0 + k0, lB0);
        gload16(bS1 + k0, lB1);
        __syncthreads();

        s16x8 af[4], bfr[4];
#pragma unroll
        for (int m = 0; m < 4; m++) af[m]  = *(const s16x8*)&As[(wr + m * 16 + fr) * 32 + kq];
#pragma unroll
        for (int n = 0; n < 4; n++) bfr[n] = *(const s16x8*)&Bs[(wc + n * 16 + fr) * 32 + kq];
#pragma unroll
        for (int m = 0; m < 4; m++)
#pragma unroll
            for (int n = 0; n < 4; n++)
                acc[m][n] = __builtin_amdgcn_mfma_f32_16x16x32_bf16(af[m], bfr[n], acc[m][n], 0, 0, 0);
        __syncthreads();
    }

    const int fq = (l >> 4) * 4;
#pragma unroll
    for (int m = 0; m < 4; m++) {
#pragma unroll
        for (int n = 0; n < 4; n++) {
            const int col = tn + wc + n * 16 + fr;
            const float bv = bias[col];
#pragma unroll
            for (int j = 0; j < 4; j++) {
                const int row = tm + wr + m * 16 + fq + j;
                float v = acc[m][n][j] + bv;
                if (MODE == 2) v = 0.5f * v * (1.0f + erff(v * 0.70710678118f));
                if (MODE == 1) {
                    ((float*)out)[(size_t)row * N + col] = v + res[(size_t)row * N + col];
                } else {
                    ((short*)out)[(size_t)row * N + col] = f2bf(v);
                }
            }
        }
    }
}

// ---------------- Flash attention v4: swapped QK^T/PV, lane-local softmax,
// 64-row q-tiles (16 rows/wave), XCD-affine block mapping so all q-tiles of a
// (b,h) share one XCD's L2 for K/V.
// grid: flat 1536, block 256 (4 waves).
__global__ __launch_bounds__(256) void attn_kernel(
    const short* __restrict__ qkv, const short* __restrict__ vTg,
    short* __restrict__ out)
{
    // bid%8 = XCD (round-robin dispatch); give XCD x the 12 heads with bh%8==x,
    // all 16 q-tiles each -> K/V working set 12*256KB = 3MB < 4MiB L2.
    const int bid = blockIdx.x;
    const int x = bid & 7;
    const int i = bid >> 3;            // 0..191
    const int bh = x + 8 * (i % 12);   // 0..95
    const int qt = i / 12;             // 0..15
    const int b = bh / 12, h = bh % 12;

    __shared__ __align__(16) short Ps[4][16][72];

    const int t = threadIdx.x;
    const int l = t & 63;
    const int w = t >> 6;
    const int lq = l & 15;   // q-column
    const int g = l >> 4;    // lane group 0..3
    const float kSc = 0.18033688011112042f;  // 0.125 * log2(e)

    const int q0 = b * 1024 + qt * 64 + w * 16;

    // Q as B-operand: lane holds Q[q=lq][d = g*8..+8 (+32)]
    s16x8 qb0, qb1;
    {
        const short* qp = qkv + ((size_t)(q0 + lq)) * 2304 + h * 64 + g * 8;
        qb0 = *(const s16x8*)qp;
        qb1 = *(const s16x8*)(qp + 32);
    }

    const short* kbase = qkv + ((size_t)(b * 1024)) * 2304 + 768 + h * 64 + g * 8;
    const short* vbase = vTg + ((size_t)(bh * 64)) * 1024 + g * 8;

    f32x4 acc[4] = {};    // acc[dt][j] = O^T[d=dt*16+g*4+j][q=lq]
    float m_run = -1e30f;
    float l_run = 0.f;

    for (int kt = 0; kt < 16; kt++) {
        // A = K fragments: lane holds K[k=kt*64+n*16+lq][d=g*8..+8 (+32)]
        s16x8 ka[4][2];
#pragma unroll
        for (int n = 0; n < 4; n++) {
            const short* kp = kbase + (size_t)(kt * 64 + n * 16 + lq) * 2304;
            ka[n][0] = *(const s16x8*)kp;
            ka[n][1] = *(const s16x8*)(kp + 32);
        }

        // S^T tiles
        f32x4 s[4];
#pragma unroll
        for (int n = 0; n < 4; n++) {
            f32x4 sv = {};
            sv = __builtin_amdgcn_mfma_f32_16x16x32_bf16(ka[n][0], qb0, sv, 0, 0, 0);
            sv = __builtin_amdgcn_mfma_f32_16x16x32_bf16(ka[n][1], qb1, sv, 0, 0, 0);
            s[n] = sv;
        }

        // A = V^T fragments (issue early: latency hides under softmax VALU)
        s16x8 va[4][2];
#pragma unroll
        for (int dt = 0; dt < 4; dt++) {
            const short* vp = vbase + (size_t)(dt * 16 + lq) * 1024 + kt * 64;
            va[dt][0] = *(const s16x8*)vp;
            va[dt][1] = *(const s16x8*)(vp + 32);
        }

        // lane-local softmax (q = lq); only 2 cross-lane shuffles
        float mx = fmaxf(fmaxf(s[0][0], s[0][1]), fmaxf(s[0][2], s[0][3]));
#pragma unroll
        for (int n = 1; n < 4; n++)
            mx = fmaxf(mx, fmaxf(fmaxf(s[n][0], s[n][1]), fmaxf(s[n][2], s[n][3])));
        mx = fmaxf(mx, __shfl_xor(mx, 16, 64));
        mx = fmaxf(mx, __shfl_xor(mx, 32, 64));
        mx *= kSc;
        const float mnew = fmaxf(m_run, mx);
        const float alpha = exp2f(m_run - mnew);
        m_run = mnew;
        float ssum = 0.f;
#pragma unroll
        for (int n = 0; n < 4; n++) {
            const float p0 = exp2f(s[n][0] * kSc - mnew);
            const float p1 = exp2f(s[n][1] * kSc - mnew);
            const float p2 = exp2f(s[n][2] * kSc - mnew);
            const float p3 = exp2f(s[n][3] * kSc - mnew);
            ssum += (p0 + p1) + (p2 + p3);
            s16x4 pk;
            pk[0] = f2bf(p0);
            pk[1] = f2bf(p1);
            pk[2] = f2bf(p2);
            pk[3] = f2bf(p3);
            // P^T[k][q] stored as Ps[q][k]: lane's 4 consecutive k = n*16+g*4..+4
            *(s16x4*)&Ps[w][lq][n * 16 + g * 4] = pk;
        }
        l_run = l_run * alpha + ssum;
#pragma unroll
        for (int dt = 0; dt < 4; dt++) {
            acc[dt][0] *= alpha; acc[dt][1] *= alpha;
            acc[dt][2] *= alpha; acc[dt][3] *= alpha;
        }

        // O^T += V^T * P  (B = P from wave-private LDS: col q=lq, k=g*8..+8)
        const s16x8 pb0 = *(const s16x8*)&Ps[w][lq][g * 8];
        const s16x8 pb1 = *(const s16x8*)&Ps[w][lq][32 + g * 8];
#pragma unroll
        for (int dt = 0; dt < 4; dt++) {
            acc[dt] = __builtin_amdgcn_mfma_f32_16x16x32_bf16(va[dt][0], pb0, acc[dt], 0, 0, 0);
            acc[dt] = __builtin_amdgcn_mfma_f32_16x16x32_bf16(va[dt][1], pb1, acc[dt], 0, 0, 0);
        }
    }

    // epilogue: finish l across the 4 lane groups, write O (8B stores)
    float ls = l_run;
    ls += __shfl_xor(ls, 16, 64);
    ls += __shfl_xor(ls, 32, 64);
    const float rinv = 1.0f / ls;
    const int qrow = q0 + lq;
#pragma unroll
    for (int dt = 0; dt < 4; dt++) {
        s16x4 ov;
#pragma unroll
        for (int j = 0; j < 4; j++) ov[j] = f2bf(acc[dt][j] * rinv);
        *(s16x4*)(out + (size_t)qrow * 768 + h * 64 + dt * 16 + g * 4) = ov;
    }
}

extern "C" void kernel_launch(void* const* d_in, const int* in_sizes, int n_in,
                              void* d_out, int out_size, void* d_ws, size_t ws_size,
                              hipStream_t stream) {
    const float* x      = (const float*)d_in[0];
    const float* n1g    = (const float*)d_in[1];
    const float* n1b    = (const float*)d_in[2];
    const float* qkv_w  = (const float*)d_in[3];
    const float* qkv_b  = (const float*)d_in[4];
    const float* proj_w = (const float*)d_in[5];
    const float* proj_b = (const float*)d_in[6];
    const float* n2g    = (const float*)d_in[7];
    const float* n2b    = (const float*)d_in[8];
    const float* fc1_w  = (const float*)d_in[9];
    const float* fc1_b  = (const float*)d_in[10];
    const float* fc2_w  = (const float*)d_in[11];
    const float* fc2_b  = (const float*)d_in[12];
    float* out = (float*)d_out;

    char* ws = (char*)d_ws;
    short* qkv_wT  = (short*)(ws + 0);           // [2304][768] bf16
    short* proj_wT = (short*)(ws + 3538944);     // [768][768]
    short* fc1_wT  = (short*)(ws + 4718592);     // [3072][768]
    short* fc2_wT  = (short*)(ws + 9437184);     // [768][3072]
    short* bufA    = (short*)(ws + 14155776);    // 8192x768 bf16 (ln1/attn_out/ln2)
    short* bufB    = (short*)(ws + 26738688);    // 8192x3072 bf16 (qkv / h1)
    short* vT      = (short*)(ws + 64487424);    // 96x64x1024 bf16 (fits in bufB tail)
    float* bufC    = (float*)(ws + 77070336);    // 8192x768 f32 (x1)

    const dim3 tb(32, 8);
    transpose_convert<<<dim3(2304 / 32, 768 / 32), tb, 0, stream>>>(qkv_w, qkv_wT, 768, 2304);
    transpose_convert<<<dim3(768 / 32, 768 / 32),  tb, 0, stream>>>(proj_w, proj_wT, 768, 768);
    transpose_convert<<<dim3(3072 / 32, 768 / 32), tb, 0, stream>>>(fc1_w, fc1_wT, 768, 3072);
    transpose_convert<<<dim3(768 / 32, 3072 / 32), tb, 0, stream>>>(fc2_w, fc2_wT, 3072, 768);

    layernorm_kernel<<<8192, 256, 0, stream>>>(x, n1g, n1b, bufA);

    gemm_bt<0><<<dim3(2304 / 128, 8192 / 128), 256, 0, stream>>>(
        bufA, qkv_wT, qkv_b, nullptr, bufB, 8192, 2304, 768);

    transpose_v<<<dim3(32, 96), 256, 0, stream>>>(bufB, vT);

    attn_kernel<<<1536, 256, 0, stream>>>(bufB, vT, bufA);

    gemm_bt<1><<<dim3(768 / 128, 8192 / 128), 256, 0, stream>>>(
        bufA, proj_wT, proj_b, x, bufC, 8192, 768, 768);

    layernorm_kernel<<<8192, 256, 0, stream>>>(bufC, n2g, n2b, bufA);

    gemm_bt<2><<<dim3(3072 / 128, 8192 / 128), 256, 0, stream>>>(
        bufA, fc1_wT, fc1_b, nullptr, bufB, 8192, 3072, 768);

    gemm_bt<1><<<dim3(768 / 128, 8192 / 128), 256, 0, stream>>>(
        bufB, fc2_wT, fc2_b, bufC, out, 8192, 768, 3072);
}

// Round 8
// 337.020 us; speedup vs baseline: 1.3710x; 1.3710x over previous
//
#include <hip/hip_runtime.h>

typedef __attribute__((ext_vector_type(8))) short s16x8;
typedef __attribute__((ext_vector_type(4))) short s16x4;
typedef __attribute__((ext_vector_type(4))) float f32x4;

static __device__ __forceinline__ short f2bf(float f) {
    unsigned u = __builtin_bit_cast(unsigned, f);
    u = (u + 0x7FFFu + ((u >> 16) & 1u)) >> 16;
    return (short)u;
}

__device__ __forceinline__ void gload16(const short* g, short* l) {
    __builtin_amdgcn_global_load_lds(
        (const __attribute__((address_space(1))) void*)g,
        (__attribute__((address_space(3))) void*)l,
        16, 0, 0);
}

// ---------------- transpose + fp32->bf16 convert:  W[K][N] f32 -> Wt[N][K] bf16
__global__ __launch_bounds__(256) void transpose_convert(
    const float* __restrict__ W, short* __restrict__ Wt, int K, int N)
{
    __shared__ float tile[32][33];
    const int bx = blockIdx.x * 32;  // N
    const int by = blockIdx.y * 32;  // K
    const int tx = threadIdx.x;      // 0..31
    const int ty = threadIdx.y;      // 0..7
    for (int i = 0; i < 32; i += 8)
        tile[ty + i][tx] = W[(size_t)(by + ty + i) * N + bx + tx];
    __syncthreads();
    for (int i = 0; i < 32; i += 8)
        Wt[(size_t)(bx + ty + i) * K + by + tx] = f2bf(tile[tx][ty + i]);
}

// ---------------- V transpose: qkv V-part [8][1024][12][64] -> vT[96][64][1024] bf16
__global__ __launch_bounds__(256) void transpose_v(
    const short* __restrict__ qkv, short* __restrict__ vT)
{
    __shared__ short tile[32][68];
    const int nt = blockIdx.x;   // 0..31
    const int bh = blockIdx.y;   // 0..95
    const int b = bh / 12, h = bh % 12;
    const int t = threadIdx.x;
    {
        const int ty = t >> 3, tx = t & 7;
        *(s16x8*)&tile[ty][tx * 8] =
            *(const s16x8*)(qkv + ((size_t)(b * 1024 + nt * 32 + ty)) * 2304 + 1536 + h * 64 + tx * 8);
    }
    __syncthreads();
    {
        const int d = t >> 2, tx = t & 3;
        s16x8 v;
#pragma unroll
        for (int i = 0; i < 8; i++) v[i] = tile[tx * 8 + i][d];
        *(s16x8*)(vT + ((size_t)(bh * 64 + d)) * 1024 + nt * 32 + tx * 8) = v;
    }
}

// ---------------- LayerNorm: x[8192][768] f32 -> out bf16
__global__ __launch_bounds__(256) void layernorm_kernel(
    const float* __restrict__ x, const float* __restrict__ g,
    const float* __restrict__ b, short* __restrict__ out)
{
    const int row = blockIdx.x;
    const float* xr = x + (size_t)row * 768;
    const int t = threadIdx.x;
    float v0 = xr[t], v1 = xr[t + 256], v2 = xr[t + 512];
    __shared__ float red[4];

    float s = v0 + v1 + v2;
    for (int off = 32; off >= 1; off >>= 1) s += __shfl_down(s, off, 64);
    if ((t & 63) == 0) red[t >> 6] = s;
    __syncthreads();
    const float mean = (red[0] + red[1] + red[2] + red[3]) * (1.0f / 768.0f);
    const float d0 = v0 - mean, d1 = v1 - mean, d2 = v2 - mean;
    __syncthreads();
    float ss = d0 * d0 + d1 * d1 + d2 * d2;
    for (int off = 32; off >= 1; off >>= 1) ss += __shfl_down(ss, off, 64);
    if ((t & 63) == 0) red[t >> 6] = ss;
    __syncthreads();
    const float var = (red[0] + red[1] + red[2] + red[3]) * (1.0f / 768.0f);
    const float rstd = rsqrtf(var + 1e-5f);
    out[(size_t)row * 768 + t]       = f2bf(d0 * rstd * g[t] + b[t]);
    out[(size_t)row * 768 + t + 256] = f2bf(d1 * rstd * g[t + 256] + b[t + 256]);
    out[(size_t)row * 768 + t + 512] = f2bf(d2 * rstd * g[t + 512] + b[t + 512]);
}

// ---------------- GEMM (m97 structure, single-buffered): C = A * Bt^T + bias
template <int MODE>
__global__ __launch_bounds__(256) void gemm_bt(
    const short* __restrict__ A, const short* __restrict__ Bt,
    const float* __restrict__ bias, const float* __restrict__ res,
    void* __restrict__ out, int M, int N, int K)
{
    __shared__ __align__(16) short As[128 * 32];
    __shared__ __align__(16) short Bs[128 * 32];

    const int t = threadIdx.x;
    const int l = t & 63;
    const int w = t >> 6;
    const int wr = (w >> 1) * 64;
    const int wc = (w & 1) * 64;
    const int tm = blockIdx.y * 128;
    const int tn = blockIdx.x * 128;

    const int lrow = l >> 2;
    const int lcol = (l & 3) * 8;
    const int ca = w * 2;
    const short* aS0 = A  + (size_t)(tm + ca * 16 + lrow) * K + lcol;
    const short* aS1 = aS0 + (size_t)16 * K;
    const short* bS0 = Bt + (size_t)(tn + ca * 16 + lrow) * K + lcol;
    const short* bS1 = bS0 + (size_t)16 * K;
    short* lA0 = &As[ca * 512];
    short* lA1 = &As[ca * 512 + 512];
    short* lB0 = &Bs[ca * 512];
    short* lB1 = &Bs[ca * 512 + 512];

    const int fr = l & 15;
    const int kq = (l >> 4) * 8;

    f32x4 acc[4][4] = {};

    for (int k0 = 0; k0 < K; k0 += 32) {
        gload16(aS0 + k0, lA0);
        gload16(aS1 + k0, lA1);
        gload16(bS0 + k0, lB0);
        gload16(bS1 + k0, lB1);
        __syncthreads();

        s16x8 af[4], bfr[4];
#pragma unroll
        for (int m = 0; m < 4; m++) af[m]  = *(const s16x8*)&As[(wr + m * 16 + fr) * 32 + kq];
#pragma unroll
        for (int n = 0; n < 4; n++) bfr[n] = *(const s16x8*)&Bs[(wc + n * 16 + fr) * 32 + kq];
#pragma unroll
        for (int m = 0; m < 4; m++)
#pragma unroll
            for (int n = 0; n < 4; n++)
                acc[m][n] = __builtin_amdgcn_mfma_f32_16x16x32_bf16(af[m], bfr[n], acc[m][n], 0, 0, 0);
        __syncthreads();
    }

    const int fq = (l >> 4) * 4;
#pragma unroll
    for (int m = 0; m < 4; m++) {
#pragma unroll
        for (int n = 0; n < 4; n++) {
            const int col = tn + wc + n * 16 + fr;
            const float bv = bias[col];
#pragma unroll
            for (int j = 0; j < 4; j++) {
                const int row = tm + wr + m * 16 + fq + j;
                float v = acc[m][n][j] + bv;
                if (MODE == 2) v = 0.5f * v * (1.0f + erff(v * 0.70710678118f));
                if (MODE == 1) {
                    ((float*)out)[(size_t)row * N + col] = v + res[(size_t)row * N + col];
                } else {
                    ((short*)out)[(size_t)row * N + col] = f2bf(v);
                }
            }
        }
    }
}

// ---------------- Flash attention v5: swapped QK^T/PV + lane-local softmax
// (v3 structure, r=2, 128-row q-tiles) + LDS staging of K/Vt via global_load_lds
// (double-buffered, XOR-swizzled both sides) + XCD-affine block mapping.
// grid: flat 768, block 256 (4 waves, each owns 32 q-rows).
__global__ __launch_bounds__(256) void attn_kernel(
    const short* __restrict__ qkv, const short* __restrict__ vTg,
    short* __restrict__ out)
{
    // bid%8 = XCD. XCD x gets the 12 heads with bh%8==x (all 8 q-tiles each):
    // K/V working set 12*256KB = 3MB < 4MiB L2 per XCD.
    const int bid = blockIdx.x;
    const int x = bid & 7;
    const int i = bid >> 3;            // 0..95
    const int bh = x + 8 * (i % 12);   // 0..95
    const int qt = i / 12;             // 0..7
    const int b = bh / 12, h = bh % 12;

    __shared__ __align__(16) short Ks[2][64 * 64];
    __shared__ __align__(16) short Vs[2][64 * 64];
    __shared__ __align__(16) short Ps[4][32][72];

    const int t = threadIdx.x;
    const int l = t & 63;
    const int w = t >> 6;
    const int lq = l & 15;   // q-column / fragment row
    const int g = l >> 4;    // lane group 0..3
    const float kSc = 0.18033688011112042f;  // 0.125 * log2(e)

    const int q0 = b * 1024 + qt * 128 + w * 32;

    // Q as B-operand: lane holds Q[q=r*16+lq][d = g*8..+8 (+32)]
    s16x8 qb[2][2];
#pragma unroll
    for (int r = 0; r < 2; r++) {
        const short* qp = qkv + ((size_t)(q0 + r * 16 + lq)) * 2304 + h * 64 + g * 8;
        qb[r][0] = *(const s16x8*)qp;
        qb[r][1] = *(const s16x8*)(qp + 32);
    }

    // Staging (wave w stages rows w*16..+15 of the 64-row tile, 2 calls x 1KB):
    // linear LDS dest row_loc = w*16 + c*8 + (l>>3), col (l&7)*16B; the global
    // source column is pre-swizzled by ((row_loc&7)<<4)B so that a swizzled
    // ds_read recovers the true layout (rule: swizzle both sides).
    const int srow = l >> 3;                    // 0..7
    const int scol = ((l & 7) ^ srow) * 8;      // pre-swizzled col (shorts)
    const short* kSrc = qkv + (size_t)(b * 1024 + w * 16 + srow) * 2304 + 768 + h * 64 + scol;
    const short* vSrc = vTg + (size_t)(bh * 64 + w * 16 + srow) * 1024 + scol;

    // prologue: stage kt=0 into buffer 0
    gload16(kSrc,                         &Ks[0][w * 1024]);
    gload16(kSrc + (size_t)8 * 2304,      &Ks[0][w * 1024 + 512]);
    gload16(vSrc,                         &Vs[0][w * 1024]);
    gload16(vSrc + (size_t)8 * 1024,      &Vs[0][w * 1024 + 512]);
    __syncthreads();

    f32x4 acc[2][4] = {};    // acc[r][dt][j] = O^T[d=dt*16+g*4+j][q=r*16+lq]
    float m_run[2] = {-1e30f, -1e30f};
    float l_run[2] = {0.f, 0.f};

    const int swz = (lq & 7) * 8;   // read-side XOR (shorts)

    int cur = 0;
    for (int kt = 0; kt < 16; kt++) {
        // prefetch kt+1 into the other buffer (async, drains at end barrier)
        if (kt < 15) {
            const short* kS = kSrc + (size_t)(kt + 1) * 64 * 2304;
            const short* vS = vSrc + (kt + 1) * 64;
            gload16(kS,                    &Ks[cur ^ 1][w * 1024]);
            gload16(kS + (size_t)8 * 2304, &Ks[cur ^ 1][w * 1024 + 512]);
            gload16(vS,                    &Vs[cur ^ 1][w * 1024]);
            gload16(vS + (size_t)8 * 1024, &Vs[cur ^ 1][w * 1024 + 512]);
        }

        // A = K fragments from LDS: K[k=n*16+lq][kk*32+g*8 .. +8]
        s16x8 ka[4][2];
#pragma unroll
        for (int n = 0; n < 4; n++) {
            const int rbase = (n * 16 + lq) * 64;
            ka[n][0] = *(const s16x8*)&Ks[cur][rbase + ((g * 8) ^ swz)];
            ka[n][1] = *(const s16x8*)&Ks[cur][rbase + ((32 + g * 8) ^ swz)];
        }

        // S^T tiles
        f32x4 s[2][4];
#pragma unroll
        for (int r = 0; r < 2; r++)
#pragma unroll
            for (int n = 0; n < 4; n++) {
                f32x4 sv = {};
                sv = __builtin_amdgcn_mfma_f32_16x16x32_bf16(ka[n][0], qb[r][0], sv, 0, 0, 0);
                sv = __builtin_amdgcn_mfma_f32_16x16x32_bf16(ka[n][1], qb[r][1], sv, 0, 0, 0);
                s[r][n] = sv;
            }

        // A = V^T fragments from LDS (issued before softmax to hide ds latency)
        s16x8 va[4][2];
#pragma unroll
        for (int dt = 0; dt < 4; dt++) {
            const int rbase = (dt * 16 + lq) * 64;
            va[dt][0] = *(const s16x8*)&Vs[cur][rbase + ((g * 8) ^ swz)];
            va[dt][1] = *(const s16x8*)&Vs[cur][rbase + ((32 + g * 8) ^ swz)];
        }

        // lane-local softmax (q = lq); 2 cross-lane shuffles per r
#pragma unroll
        for (int r = 0; r < 2; r++) {
            float mx = fmaxf(fmaxf(s[r][0][0], s[r][0][1]), fmaxf(s[r][0][2], s[r][0][3]));
#pragma unroll
            for (int n = 1; n < 4; n++)
                mx = fmaxf(mx, fmaxf(fmaxf(s[r][n][0], s[r][n][1]), fmaxf(s[r][n][2], s[r][n][3])));
            mx = fmaxf(mx, __shfl_xor(mx, 16, 64));
            mx = fmaxf(mx, __shfl_xor(mx, 32, 64));
            mx *= kSc;
            const float mnew = fmaxf(m_run[r], mx);
            const float alpha = exp2f(m_run[r] - mnew);
            m_run[r] = mnew;
            float ssum = 0.f;
#pragma unroll
            for (int n = 0; n < 4; n++) {
                const float p0 = exp2f(s[r][n][0] * kSc - mnew);
                const float p1 = exp2f(s[r][n][1] * kSc - mnew);
                const float p2 = exp2f(s[r][n][2] * kSc - mnew);
                const float p3 = exp2f(s[r][n][3] * kSc - mnew);
                ssum += (p0 + p1) + (p2 + p3);
                s16x4 pk;
                pk[0] = f2bf(p0);
                pk[1] = f2bf(p1);
                pk[2] = f2bf(p2);
                pk[3] = f2bf(p3);
                *(s16x4*)&Ps[w][r * 16 + lq][n * 16 + g * 4] = pk;
            }
            l_run[r] = l_run[r] * alpha + ssum;
#pragma unroll
            for (int dt = 0; dt < 4; dt++) {
                acc[r][dt][0] *= alpha; acc[r][dt][1] *= alpha;
                acc[r][dt][2] *= alpha; acc[r][dt][3] *= alpha;
            }
        }

        // O^T += V^T * P  (B = P from wave-private LDS; DS in-order per wave)
#pragma unroll
        for (int r = 0; r < 2; r++) {
            const s16x8 pb0 = *(const s16x8*)&Ps[w][r * 16 + lq][g * 8];
            const s16x8 pb1 = *(const s16x8*)&Ps[w][r * 16 + lq][32 + g * 8];
#pragma unroll
            for (int dt = 0; dt < 4; dt++) {
                acc[r][dt] = __builtin_amdgcn_mfma_f32_16x16x32_bf16(va[dt][0], pb0, acc[r][dt], 0, 0, 0);
                acc[r][dt] = __builtin_amdgcn_mfma_f32_16x16x32_bf16(va[dt][1], pb1, acc[r][dt], 0, 0, 0);
            }
        }

        __syncthreads();   // drains prefetch vmcnt; all waves done with buf cur
        if (kt < 15) cur ^= 1;
    }

    // epilogue: finish l across the 4 lane groups, write O (8B stores)
#pragma unroll
    for (int r = 0; r < 2; r++) {
        float ls = l_run[r];
        ls += __shfl_xor(ls, 16, 64);
        ls += __shfl_xor(ls, 32, 64);
        const float rinv = 1.0f / ls;
        const int qrow = q0 + r * 16 + lq;
#pragma unroll
        for (int dt = 0; dt < 4; dt++) {
            s16x4 ov;
#pragma unroll
            for (int j = 0; j < 4; j++) ov[j] = f2bf(acc[r][dt][j] * rinv);
            *(s16x4*)(out + (size_t)qrow * 768 + h * 64 + dt * 16 + g * 4) = ov;
        }
    }
}

extern "C" void kernel_launch(void* const* d_in, const int* in_sizes, int n_in,
                              void* d_out, int out_size, void* d_ws, size_t ws_size,
                              hipStream_t stream) {
    const float* x      = (const float*)d_in[0];
    const float* n1g    = (const float*)d_in[1];
    const float* n1b    = (const float*)d_in[2];
    const float* qkv_w  = (const float*)d_in[3];
    const float* qkv_b  = (const float*)d_in[4];
    const float* proj_w = (const float*)d_in[5];
    const float* proj_b = (const float*)d_in[6];
    const float* n2g    = (const float*)d_in[7];
    const float* n2b    = (const float*)d_in[8];
    const float* fc1_w  = (const float*)d_in[9];
    const float* fc1_b  = (const float*)d_in[10];
    const float* fc2_w  = (const float*)d_in[11];
    const float* fc2_b  = (const float*)d_in[12];
    float* out = (float*)d_out;

    char* ws = (char*)d_ws;
    short* qkv_wT  = (short*)(ws + 0);           // [2304][768] bf16
    short* proj_wT = (short*)(ws + 3538944);     // [768][768]
    short* fc1_wT  = (short*)(ws + 4718592);     // [3072][768]
    short* fc2_wT  = (short*)(ws + 9437184);     // [768][3072]
    short* bufA    = (short*)(ws + 14155776);    // 8192x768 bf16 (ln1/attn_out/ln2)
    short* bufB    = (short*)(ws + 26738688);    // 8192x3072 bf16 (qkv / h1)
    short* vT      = (short*)(ws + 64487424);    // 96x64x1024 bf16 (fits in bufB tail)
    float* bufC    = (float*)(ws + 77070336);    // 8192x768 f32 (x1)

    const dim3 tb(32, 8);
    transpose_convert<<<dim3(2304 / 32, 768 / 32), tb, 0, stream>>>(qkv_w, qkv_wT, 768, 2304);
    transpose_convert<<<dim3(768 / 32, 768 / 32),  tb, 0, stream>>>(proj_w, proj_wT, 768, 768);
    transpose_convert<<<dim3(3072 / 32, 768 / 32), tb, 0, stream>>>(fc1_w, fc1_wT, 768, 3072);
    transpose_convert<<<dim3(768 / 32, 3072 / 32), tb, 0, stream>>>(fc2_w, fc2_wT, 3072, 768);

    layernorm_kernel<<<8192, 256, 0, stream>>>(x, n1g, n1b, bufA);

    gemm_bt<0><<<dim3(2304 / 128, 8192 / 128), 256, 0, stream>>>(
        bufA, qkv_wT, qkv_b, nullptr, bufB, 8192, 2304, 768);

    transpose_v<<<dim3(32, 96), 256, 0, stream>>>(bufB, vT);

    attn_kernel<<<768, 256, 0, stream>>>(bufB, vT, bufA);

    gemm_bt<1><<<dim3(768 / 128, 8192 / 128), 256, 0, stream>>>(
        bufA, proj_wT, proj_b, x, bufC, 8192, 768, 768);

    layernorm_kernel<<<8192, 256, 0, stream>>>(bufC, n2g, n2b, bufA);

    gemm_bt<2><<<dim3(3072 / 128, 8192 / 128), 256, 0, stream>>>(
        bufA, fc1_wT, fc1_b, nullptr, bufB, 8192, 3072, 768);

    gemm_bt<1><<<dim3(768 / 128, 8192 / 128), 256, 0, stream>>>(
        bufB, fc2_wT, fc2_b, bufC, out, 8192, 768, 3072);
}

// Round 9
// 312.276 us; speedup vs baseline: 1.4796x; 1.0792x over previous
//
#include <hip/hip_runtime.h>

typedef __attribute__((ext_vector_type(8))) short s16x8;
typedef __attribute__((ext_vector_type(4))) short s16x4;
typedef __attribute__((ext_vector_type(4))) float f32x4;

static __device__ __forceinline__ short f2bf(float f) {
    unsigned u = __builtin_bit_cast(unsigned, f);
    u = (u + 0x7FFFu + ((u >> 16) & 1u)) >> 16;
    return (short)u;
}

__device__ __forceinline__ void gload16(const short* g, short* l) {
    __builtin_amdgcn_global_load_lds(
        (const __attribute__((address_space(1))) void*)g,
        (__attribute__((address_space(3))) void*)l,
        16, 0, 0);
}

// ---------------- transpose + fp32->bf16 convert:  W[K][N] f32 -> Wt[N][K] bf16
__global__ __launch_bounds__(256) void transpose_convert(
    const float* __restrict__ W, short* __restrict__ Wt, int K, int N)
{
    __shared__ float tile[32][33];
    const int bx = blockIdx.x * 32;  // N
    const int by = blockIdx.y * 32;  // K
    const int tx = threadIdx.x;      // 0..31
    const int ty = threadIdx.y;      // 0..7
    for (int i = 0; i < 32; i += 8)
        tile[ty + i][tx] = W[(size_t)(by + ty + i) * N + bx + tx];
    __syncthreads();
    for (int i = 0; i < 32; i += 8)
        Wt[(size_t)(bx + ty + i) * K + by + tx] = f2bf(tile[tx][ty + i]);
}

// ---------------- V transpose: qkv V-part [8][1024][12][64] -> vT[96][64][1024] bf16
__global__ __launch_bounds__(256) void transpose_v(
    const short* __restrict__ qkv, short* __restrict__ vT)
{
    __shared__ short tile[32][68];
    const int nt = blockIdx.x;   // 0..31
    const int bh = blockIdx.y;   // 0..95
    const int b = bh / 12, h = bh % 12;
    const int t = threadIdx.x;
    {
        const int ty = t >> 3, tx = t & 7;
        *(s16x8*)&tile[ty][tx * 8] =
            *(const s16x8*)(qkv + ((size_t)(b * 1024 + nt * 32 + ty)) * 2304 + 1536 + h * 64 + tx * 8);
    }
    __syncthreads();
    {
        const int d = t >> 2, tx = t & 3;
        s16x8 v;
#pragma unroll
        for (int i = 0; i < 8; i++) v[i] = tile[tx * 8 + i][d];
        *(s16x8*)(vT + ((size_t)(bh * 64 + d)) * 1024 + nt * 32 + tx * 8) = v;
    }
}

// ---------------- LayerNorm: x[8192][768] f32 -> out bf16
__global__ __launch_bounds__(256) void layernorm_kernel(
    const float* __restrict__ x, const float* __restrict__ g,
    const float* __restrict__ b, short* __restrict__ out)
{
    const int row = blockIdx.x;
    const float* xr = x + (size_t)row * 768;
    const int t = threadIdx.x;
    float v0 = xr[t], v1 = xr[t + 256], v2 = xr[t + 512];
    __shared__ float red[4];

    float s = v0 + v1 + v2;
    for (int off = 32; off >= 1; off >>= 1) s += __shfl_down(s, off, 64);
    if ((t & 63) == 0) red[t >> 6] = s;
    __syncthreads();
    const float mean = (red[0] + red[1] + red[2] + red[3]) * (1.0f / 768.0f);
    const float d0 = v0 - mean, d1 = v1 - mean, d2 = v2 - mean;
    __syncthreads();
    float ss = d0 * d0 + d1 * d1 + d2 * d2;
    for (int off = 32; off >= 1; off >>= 1) ss += __shfl_down(ss, off, 64);
    if ((t & 63) == 0) red[t >> 6] = ss;
    __syncthreads();
    const float var = (red[0] + red[1] + red[2] + red[3]) * (1.0f / 768.0f);
    const float rstd = rsqrtf(var + 1e-5f);
    out[(size_t)row * 768 + t]       = f2bf(d0 * rstd * g[t] + b[t]);
    out[(size_t)row * 768 + t + 256] = f2bf(d1 * rstd * g[t + 256] + b[t + 256]);
    out[(size_t)row * 768 + t + 512] = f2bf(d2 * rstd * g[t + 512] + b[t + 512]);
}

// ---------------- GEMM v2: BK=64, XOR-swizzled LDS, XCD-affine flat grid.
// C[M][N] = A[M][K](bf16) * Bt[N][K]^T + bias. M must be 8192 (64 row-panels).
// grid = 64 * (N/128) flat; XCD x owns row-panels r%8==x, iterates cols first
// so the A-panel stays in that XCD's L2.
template <int MODE>
__global__ __launch_bounds__(256) void gemm_bt(
    const short* __restrict__ A, const short* __restrict__ Bt,
    const float* __restrict__ bias, const float* __restrict__ res,
    void* __restrict__ out, int M, int N, int K)
{
    __shared__ __align__(16) short As[128 * 64];
    __shared__ __align__(16) short Bs[128 * 64];

    const int t = threadIdx.x;
    const int l = t & 63;
    const int w = t >> 6;
    const int wr = (w >> 1) * 64;
    const int wc = (w & 1) * 64;

    const int ncol = N >> 7;
    const int xcd = blockIdx.x & 7;
    const int idx = blockIdx.x >> 3;
    const int tn = (idx % ncol) << 7;
    const int tm = ((idx / ncol) * 8 + xcd) << 7;

    // staging: 16 chunks of (8 rows x 128B) per matrix; wave w stages chunks
    // 4w..4w+3. gload16 writes linearly; the global source column is
    // pre-swizzled (slot ^ row&7) so a swizzled ds_read recovers true layout.
    const int srow = l >> 3;                  // 0..7 within chunk
    const int scol = ((l & 7) ^ srow) * 8;    // shorts
    const int c0 = w * 4;
    const short* aS[4]; const short* bS[4];
#pragma unroll
    for (int c = 0; c < 4; c++) {
        const int row = (c0 + c) * 8 + srow;
        aS[c] = A  + (size_t)(tm + row) * K + scol;
        bS[c] = Bt + (size_t)(tn + row) * K + scol;
    }

    const int fr = l & 15;
    const int g = l >> 4;
    const int sl = fr & 7;            // row component of the XOR swizzle

    f32x4 acc[4][4] = {};

    for (int k0 = 0; k0 < K; k0 += 64) {
#pragma unroll
        for (int c = 0; c < 4; c++) {
            gload16(aS[c] + k0, &As[(c0 + c) * 512]);
            gload16(bS[c] + k0, &Bs[(c0 + c) * 512]);
        }
        __syncthreads();   // drains vmcnt -> tiles complete

        s16x8 af[4][2], bf[4][2];
#pragma unroll
        for (int m = 0; m < 4; m++) {
            const int rbase = (wr + m * 16 + fr) * 64;
            af[m][0] = *(const s16x8*)&As[rbase + ((g ^ sl) * 8)];
            af[m][1] = *(const s16x8*)&As[rbase + (((4 + g) ^ sl) * 8)];
        }
#pragma unroll
        for (int n = 0; n < 4; n++) {
            const int rbase = (wc + n * 16 + fr) * 64;
            bf[n][0] = *(const s16x8*)&Bs[rbase + ((g ^ sl) * 8)];
            bf[n][1] = *(const s16x8*)&Bs[rbase + (((4 + g) ^ sl) * 8)];
        }
#pragma unroll
        for (int m = 0; m < 4; m++)
#pragma unroll
            for (int n = 0; n < 4; n++) {
                acc[m][n] = __builtin_amdgcn_mfma_f32_16x16x32_bf16(af[m][0], bf[n][0], acc[m][n], 0, 0, 0);
                acc[m][n] = __builtin_amdgcn_mfma_f32_16x16x32_bf16(af[m][1], bf[n][1], acc[m][n], 0, 0, 0);
            }
        __syncthreads();   // protect LDS reuse next iter
    }

    const int fq = (l >> 4) * 4;
#pragma unroll
    for (int m = 0; m < 4; m++) {
#pragma unroll
        for (int n = 0; n < 4; n++) {
            const int col = tn + wc + n * 16 + fr;
            const float bv = bias[col];
#pragma unroll
            for (int j = 0; j < 4; j++) {
                const int row = tm + wr + m * 16 + fq + j;
                float v = acc[m][n][j] + bv;
                if (MODE == 2) v = 0.5f * v * (1.0f + erff(v * 0.70710678118f));
                if (MODE == 1) {
                    ((float*)out)[(size_t)row * N + col] = v + res[(size_t)row * N + col];
                } else {
                    ((short*)out)[(size_t)row * N + col] = f2bf(v);
                }
            }
        }
    }
}

// ---------------- Flash attention v5: swapped QK^T/PV + lane-local softmax
// (r=2, 128-row q-tiles) + LDS staging of K/Vt via global_load_lds
// (double-buffered, XOR-swizzled both sides) + XCD-affine block mapping.
// grid: flat 768, block 256 (4 waves, each owns 32 q-rows).
__global__ __launch_bounds__(256) void attn_kernel(
    const short* __restrict__ qkv, const short* __restrict__ vTg,
    short* __restrict__ out)
{
    const int bid = blockIdx.x;
    const int x = bid & 7;
    const int i = bid >> 3;            // 0..95
    const int bh = x + 8 * (i % 12);   // 0..95
    const int qt = i / 12;             // 0..7
    const int b = bh / 12, h = bh % 12;

    __shared__ __align__(16) short Ks[2][64 * 64];
    __shared__ __align__(16) short Vs[2][64 * 64];
    __shared__ __align__(16) short Ps[4][32][72];

    const int t = threadIdx.x;
    const int l = t & 63;
    const int w = t >> 6;
    const int lq = l & 15;   // q-column / fragment row
    const int g = l >> 4;    // lane group 0..3
    const float kSc = 0.18033688011112042f;  // 0.125 * log2(e)

    const int q0 = b * 1024 + qt * 128 + w * 32;

    // Q as B-operand: lane holds Q[q=r*16+lq][d = g*8..+8 (+32)]
    s16x8 qb[2][2];
#pragma unroll
    for (int r = 0; r < 2; r++) {
        const short* qp = qkv + ((size_t)(q0 + r * 16 + lq)) * 2304 + h * 64 + g * 8;
        qb[r][0] = *(const s16x8*)qp;
        qb[r][1] = *(const s16x8*)(qp + 32);
    }

    const int srow = l >> 3;                    // 0..7
    const int scol = ((l & 7) ^ srow) * 8;      // pre-swizzled col (shorts)
    const short* kSrc = qkv + (size_t)(b * 1024 + w * 16 + srow) * 2304 + 768 + h * 64 + scol;
    const short* vSrc = vTg + (size_t)(bh * 64 + w * 16 + srow) * 1024 + scol;

    // prologue: stage kt=0 into buffer 0
    gload16(kSrc,                         &Ks[0][w * 1024]);
    gload16(kSrc + (size_t)8 * 2304,      &Ks[0][w * 1024 + 512]);
    gload16(vSrc,                         &Vs[0][w * 1024]);
    gload16(vSrc + (size_t)8 * 1024,      &Vs[0][w * 1024 + 512]);
    __syncthreads();

    f32x4 acc[2][4] = {};    // acc[r][dt][j] = O^T[d=dt*16+g*4+j][q=r*16+lq]
    float m_run[2] = {-1e30f, -1e30f};
    float l_run[2] = {0.f, 0.f};

    const int swz = (lq & 7) * 8;   // read-side XOR (shorts)

    int cur = 0;
    for (int kt = 0; kt < 16; kt++) {
        if (kt < 15) {
            const short* kS = kSrc + (size_t)(kt + 1) * 64 * 2304;
            const short* vS = vSrc + (kt + 1) * 64;
            gload16(kS,                    &Ks[cur ^ 1][w * 1024]);
            gload16(kS + (size_t)8 * 2304, &Ks[cur ^ 1][w * 1024 + 512]);
            gload16(vS,                    &Vs[cur ^ 1][w * 1024]);
            gload16(vS + (size_t)8 * 1024, &Vs[cur ^ 1][w * 1024 + 512]);
        }

        // A = K fragments from LDS: K[k=n*16+lq][kk*32+g*8 .. +8]
        s16x8 ka[4][2];
#pragma unroll
        for (int n = 0; n < 4; n++) {
            const int rbase = (n * 16 + lq) * 64;
            ka[n][0] = *(const s16x8*)&Ks[cur][rbase + ((g * 8) ^ swz)];
            ka[n][1] = *(const s16x8*)&Ks[cur][rbase + ((32 + g * 8) ^ swz)];
        }

        f32x4 s[2][4];
#pragma unroll
        for (int r = 0; r < 2; r++)
#pragma unroll
            for (int n = 0; n < 4; n++) {
                f32x4 sv = {};
                sv = __builtin_amdgcn_mfma_f32_16x16x32_bf16(ka[n][0], qb[r][0], sv, 0, 0, 0);
                sv = __builtin_amdgcn_mfma_f32_16x16x32_bf16(ka[n][1], qb[r][1], sv, 0, 0, 0);
                s[r][n] = sv;
            }

        s16x8 va[4][2];
#pragma unroll
        for (int dt = 0; dt < 4; dt++) {
            const int rbase = (dt * 16 + lq) * 64;
            va[dt][0] = *(const s16x8*)&Vs[cur][rbase + ((g * 8) ^ swz)];
            va[dt][1] = *(const s16x8*)&Vs[cur][rbase + ((32 + g * 8) ^ swz)];
        }

#pragma unroll
        for (int r = 0; r < 2; r++) {
            float mx = fmaxf(fmaxf(s[r][0][0], s[r][0][1]), fmaxf(s[r][0][2], s[r][0][3]));
#pragma unroll
            for (int n = 1; n < 4; n++)
                mx = fmaxf(mx, fmaxf(fmaxf(s[r][n][0], s[r][n][1]), fmaxf(s[r][n][2], s[r][n][3])));
            mx = fmaxf(mx, __shfl_xor(mx, 16, 64));
            mx = fmaxf(mx, __shfl_xor(mx, 32, 64));
            mx *= kSc;
            const float mnew = fmaxf(m_run[r], mx);
            const float alpha = exp2f(m_run[r] - mnew);
            m_run[r] = mnew;
            float ssum = 0.f;
#pragma unroll
            for (int n = 0; n < 4; n++) {
                const float p0 = exp2f(s[r][n][0] * kSc - mnew);
                const float p1 = exp2f(s[r][n][1] * kSc - mnew);
                const float p2 = exp2f(s[r][n][2] * kSc - mnew);
                const float p3 = exp2f(s[r][n][3] * kSc - mnew);
                ssum += (p0 + p1) + (p2 + p3);
                s16x4 pk;
                pk[0] = f2bf(p0);
                pk[1] = f2bf(p1);
                pk[2] = f2bf(p2);
                pk[3] = f2bf(p3);
                *(s16x4*)&Ps[w][r * 16 + lq][n * 16 + g * 4] = pk;
            }
            l_run[r] = l_run[r] * alpha + ssum;
#pragma unroll
            for (int dt = 0; dt < 4; dt++) {
                acc[r][dt][0] *= alpha; acc[r][dt][1] *= alpha;
                acc[r][dt][2] *= alpha; acc[r][dt][3] *= alpha;
            }
        }

#pragma unroll
        for (int r = 0; r < 2; r++) {
            const s16x8 pb0 = *(const s16x8*)&Ps[w][r * 16 + lq][g * 8];
            const s16x8 pb1 = *(const s16x8*)&Ps[w][r * 16 + lq][32 + g * 8];
#pragma unroll
            for (int dt = 0; dt < 4; dt++) {
                acc[r][dt] = __builtin_amdgcn_mfma_f32_16x16x32_bf16(va[dt][0], pb0, acc[r][dt], 0, 0, 0);
                acc[r][dt] = __builtin_amdgcn_mfma_f32_16x16x32_bf16(va[dt][1], pb1, acc[r][dt], 0, 0, 0);
            }
        }

        __syncthreads();
        if (kt < 15) cur ^= 1;
    }

#pragma unroll
    for (int r = 0; r < 2; r++) {
        float ls = l_run[r];
        ls += __shfl_xor(ls, 16, 64);
        ls += __shfl_xor(ls, 32, 64);
        const float rinv = 1.0f / ls;
        const int qrow = q0 + r * 16 + lq;
#pragma unroll
        for (int dt = 0; dt < 4; dt++) {
            s16x4 ov;
#pragma unroll
            for (int j = 0; j < 4; j++) ov[j] = f2bf(acc[r][dt][j] * rinv);
            *(s16x4*)(out + (size_t)qrow * 768 + h * 64 + dt * 16 + g * 4) = ov;
        }
    }
}

extern "C" void kernel_launch(void* const* d_in, const int* in_sizes, int n_in,
                              void* d_out, int out_size, void* d_ws, size_t ws_size,
                              hipStream_t stream) {
    const float* x      = (const float*)d_in[0];
    const float* n1g    = (const float*)d_in[1];
    const float* n1b    = (const float*)d_in[2];
    const float* qkv_w  = (const float*)d_in[3];
    const float* qkv_b  = (const float*)d_in[4];
    const float* proj_w = (const float*)d_in[5];
    const float* proj_b = (const float*)d_in[6];
    const float* n2g    = (const float*)d_in[7];
    const float* n2b    = (const float*)d_in[8];
    const float* fc1_w  = (const float*)d_in[9];
    const float* fc1_b  = (const float*)d_in[10];
    const float* fc2_w  = (const float*)d_in[11];
    const float* fc2_b  = (const float*)d_in[12];
    float* out = (float*)d_out;

    char* ws = (char*)d_ws;
    short* qkv_wT  = (short*)(ws + 0);           // [2304][768] bf16
    short* proj_wT = (short*)(ws + 3538944);     // [768][768]
    short* fc1_wT  = (short*)(ws + 4718592);     // [3072][768]
    short* fc2_wT  = (short*)(ws + 9437184);     // [768][3072]
    short* bufA    = (short*)(ws + 14155776);    // 8192x768 bf16 (ln1/attn_out/ln2)
    short* bufB    = (short*)(ws + 26738688);    // 8192x3072 bf16 (qkv / h1)
    short* vT      = (short*)(ws + 64487424);    // 96x64x1024 bf16 (fits in bufB tail)
    float* bufC    = (float*)(ws + 77070336);    // 8192x768 f32 (x1)

    const dim3 tb(32, 8);
    transpose_convert<<<dim3(2304 / 32, 768 / 32), tb, 0, stream>>>(qkv_w, qkv_wT, 768, 2304);
    transpose_convert<<<dim3(768 / 32, 768 / 32),  tb, 0, stream>>>(proj_w, proj_wT, 768, 768);
    transpose_convert<<<dim3(3072 / 32, 768 / 32), tb, 0, stream>>>(fc1_w, fc1_wT, 768, 3072);
    transpose_convert<<<dim3(768 / 32, 3072 / 32), tb, 0, stream>>>(fc2_w, fc2_wT, 3072, 768);

    layernorm_kernel<<<8192, 256, 0, stream>>>(x, n1g, n1b, bufA);

    gemm_bt<0><<<64 * (2304 / 128), 256, 0, stream>>>(
        bufA, qkv_wT, qkv_b, nullptr, bufB, 8192, 2304, 768);

    transpose_v<<<dim3(32, 96), 256, 0, stream>>>(bufB, vT);

    attn_kernel<<<768, 256, 0, stream>>>(bufB, vT, bufA);

    gemm_bt<1><<<64 * (768 / 128), 256, 0, stream>>>(
        bufA, proj_wT, proj_b, x, bufC, 8192, 768, 768);

    layernorm_kernel<<<8192, 256, 0, stream>>>(bufC, n2g, n2b, bufA);

    gemm_bt<2><<<64 * (3072 / 128), 256, 0, stream>>>(
        bufA, fc1_wT, fc1_b, nullptr, bufB, 8192, 3072, 768);

    gemm_bt<1><<<64 * (768 / 128), 256, 0, stream>>>(
        bufB, fc2_wT, fc2_b, bufC, out, 8192, 768, 3072);
}

// Round 10
// 279.941 us; speedup vs baseline: 1.6505x; 1.1155x over previous
//
#include <hip/hip_runtime.h>

typedef __attribute__((ext_vector_type(8))) short s16x8;
typedef __attribute__((ext_vector_type(4))) short s16x4;
typedef __attribute__((ext_vector_type(4))) float f32x4;

static __device__ __forceinline__ short f2bf(float f) {
    unsigned u = __builtin_bit_cast(unsigned, f);
    u = (u + 0x7FFFu + ((u >> 16) & 1u)) >> 16;
    return (short)u;
}

__device__ __forceinline__ void gload16(const short* g, short* l) {
    __builtin_amdgcn_global_load_lds(
        (const __attribute__((address_space(1))) void*)g,
        (__attribute__((address_space(3))) void*)l,
        16, 0, 0);
}

// ---------------- transpose + fp32->bf16 convert:  W[K][N] f32 -> Wt[N][K] bf16
__global__ __launch_bounds__(256) void transpose_convert(
    const float* __restrict__ W, short* __restrict__ Wt, int K, int N)
{
    __shared__ float tile[32][33];
    const int bx = blockIdx.x * 32;  // N
    const int by = blockIdx.y * 32;  // K
    const int tx = threadIdx.x;      // 0..31
    const int ty = threadIdx.y;      // 0..7
    for (int i = 0; i < 32; i += 8)
        tile[ty + i][tx] = W[(size_t)(by + ty + i) * N + bx + tx];
    __syncthreads();
    for (int i = 0; i < 32; i += 8)
        Wt[(size_t)(bx + ty + i) * K + by + tx] = f2bf(tile[tx][ty + i]);
}

// ---------------- LayerNorm: x[8192][768] f32 -> out bf16
__global__ __launch_bounds__(256) void layernorm_kernel(
    const float* __restrict__ x, const float* __restrict__ g,
    const float* __restrict__ b, short* __restrict__ out)
{
    const int row = blockIdx.x;
    const float* xr = x + (size_t)row * 768;
    const int t = threadIdx.x;
    float v0 = xr[t], v1 = xr[t + 256], v2 = xr[t + 512];
    __shared__ float red[4];

    float s = v0 + v1 + v2;
    for (int off = 32; off >= 1; off >>= 1) s += __shfl_down(s, off, 64);
    if ((t & 63) == 0) red[t >> 6] = s;
    __syncthreads();
    const float mean = (red[0] + red[1] + red[2] + red[3]) * (1.0f / 768.0f);
    const float d0 = v0 - mean, d1 = v1 - mean, d2 = v2 - mean;
    __syncthreads();
    float ss = d0 * d0 + d1 * d1 + d2 * d2;
    for (int off = 32; off >= 1; off >>= 1) ss += __shfl_down(ss, off, 64);
    if ((t & 63) == 0) red[t >> 6] = ss;
    __syncthreads();
    const float var = (red[0] + red[1] + red[2] + red[3]) * (1.0f / 768.0f);
    const float rstd = rsqrtf(var + 1e-5f);
    out[(size_t)row * 768 + t]       = f2bf(d0 * rstd * g[t] + b[t]);
    out[(size_t)row * 768 + t + 256] = f2bf(d1 * rstd * g[t + 256] + b[t + 256]);
    out[(size_t)row * 768 + t + 512] = f2bf(d2 * rstd * g[t + 512] + b[t + 512]);
}

// ---------------- GEMM v2: BK=64, XOR-swizzled LDS, XCD-affine flat grid.
// C[M][N] = A[M][K](bf16) * Bt[N][K]^T + bias. M must be 8192 (64 row-panels).
// MODE 0: out bf16 = acc + bias
// MODE 1: out f32  = acc + bias + res
// MODE 2: out bf16 = gelu(acc + bias)
// MODE 3: QKV: cols<1536 -> bf16 out; cols>=1536 (V) -> vtout[bh*64+d][n] s16x4
template <int MODE>
__global__ __launch_bounds__(256) void gemm_bt(
    const short* __restrict__ A, const short* __restrict__ Bt,
    const float* __restrict__ bias, const float* __restrict__ res,
    void* __restrict__ out, short* __restrict__ vtout, int M, int N, int K)
{
    __shared__ __align__(16) short As[128 * 64];
    __shared__ __align__(16) short Bs[128 * 64];

    const int t = threadIdx.x;
    const int l = t & 63;
    const int w = t >> 6;
    const int wr = (w >> 1) * 64;
    const int wc = (w & 1) * 64;

    const int ncol = N >> 7;
    const int xcd = blockIdx.x & 7;
    const int idx = blockIdx.x >> 3;
    const int tn = (idx % ncol) << 7;
    const int tm = ((idx / ncol) * 8 + xcd) << 7;

    const int srow = l >> 3;                  // 0..7 within chunk
    const int scol = ((l & 7) ^ srow) * 8;    // pre-swizzled col (shorts)
    const int c0 = w * 4;
    const short* aS[4]; const short* bS[4];
#pragma unroll
    for (int c = 0; c < 4; c++) {
        const int row = (c0 + c) * 8 + srow;
        aS[c] = A  + (size_t)(tm + row) * K + scol;
        bS[c] = Bt + (size_t)(tn + row) * K + scol;
    }

    const int fr = l & 15;
    const int g = l >> 4;
    const int sl = fr & 7;            // row component of the XOR swizzle

    f32x4 acc[4][4] = {};

    for (int k0 = 0; k0 < K; k0 += 64) {
#pragma unroll
        for (int c = 0; c < 4; c++) {
            gload16(aS[c] + k0, &As[(c0 + c) * 512]);
            gload16(bS[c] + k0, &Bs[(c0 + c) * 512]);
        }
        __syncthreads();

        s16x8 af[4][2], bf[4][2];
#pragma unroll
        for (int m = 0; m < 4; m++) {
            const int rbase = (wr + m * 16 + fr) * 64;
            af[m][0] = *(const s16x8*)&As[rbase + ((g ^ sl) * 8)];
            af[m][1] = *(const s16x8*)&As[rbase + (((4 + g) ^ sl) * 8)];
        }
#pragma unroll
        for (int n = 0; n < 4; n++) {
            const int rbase = (wc + n * 16 + fr) * 64;
            bf[n][0] = *(const s16x8*)&Bs[rbase + ((g ^ sl) * 8)];
            bf[n][1] = *(const s16x8*)&Bs[rbase + (((4 + g) ^ sl) * 8)];
        }
#pragma unroll
        for (int m = 0; m < 4; m++)
#pragma unroll
            for (int n = 0; n < 4; n++) {
                acc[m][n] = __builtin_amdgcn_mfma_f32_16x16x32_bf16(af[m][0], bf[n][0], acc[m][n], 0, 0, 0);
                acc[m][n] = __builtin_amdgcn_mfma_f32_16x16x32_bf16(af[m][1], bf[n][1], acc[m][n], 0, 0, 0);
            }
        __syncthreads();
    }

    const int fq = (l >> 4) * 4;
#pragma unroll
    for (int m = 0; m < 4; m++) {
#pragma unroll
        for (int n = 0; n < 4; n++) {
            const int col = tn + wc + n * 16 + fr;
            const float bv = bias[col];
            if (MODE == 3 && col >= 1536) {
                // V-part: write transposed directly, 4 consecutive n_seq -> 8B store
                const int row0 = tm + wr + m * 16 + fq;
                const int bb = row0 >> 10;
                const int nseq = row0 & 1023;
                s16x4 ov;
#pragma unroll
                for (int j = 0; j < 4; j++) ov[j] = f2bf(acc[m][n][j] + bv);
                *(s16x4*)(vtout + (((size_t)(bb * 768 + (col - 1536))) << 10) + nseq) = ov;
            } else {
#pragma unroll
                for (int j = 0; j < 4; j++) {
                    const int row = tm + wr + m * 16 + fq + j;
                    float v = acc[m][n][j] + bv;
                    if (MODE == 2) v = 0.5f * v * (1.0f + erff(v * 0.70710678118f));
                    if (MODE == 1) {
                        ((float*)out)[(size_t)row * N + col] = v + res[(size_t)row * N + col];
                    } else {
                        ((short*)out)[(size_t)row * N + col] = f2bf(v);
                    }
                }
            }
        }
    }
}

// ---------------- Flash attention v6: swapped QK^T/PV, lane-local softmax,
// defer-max (THR=8), cvt_pk P packing, LDS-staged K/Vt (double-buffered,
// XOR-swizzled both sides), XCD-affine mapping.
// grid: flat 768, block 256 (4 waves, each owns 32 q-rows).
__global__ __launch_bounds__(256) void attn_kernel(
    const short* __restrict__ qkv, const short* __restrict__ vTg,
    short* __restrict__ out)
{
    const int bid = blockIdx.x;
    const int x = bid & 7;
    const int i = bid >> 3;            // 0..95
    const int bh = x + 8 * (i % 12);   // 0..95
    const int qt = i / 12;             // 0..7
    const int b = bh / 12, h = bh % 12;

    __shared__ __align__(16) short Ks[2][64 * 64];
    __shared__ __align__(16) short Vs[2][64 * 64];
    __shared__ __align__(16) short Ps[4][32][72];

    const int t = threadIdx.x;
    const int l = t & 63;
    const int w = t >> 6;
    const int lq = l & 15;   // q-column / fragment row
    const int g = l >> 4;    // lane group 0..3
    const float kSc = 0.18033688011112042f;  // 0.125 * log2(e)

    const int q0 = b * 1024 + qt * 128 + w * 32;

    // Q as B-operand: lane holds Q[q=r*16+lq][d = g*8..+8 (+32)]
    s16x8 qb[2][2];
#pragma unroll
    for (int r = 0; r < 2; r++) {
        const short* qp = qkv + ((size_t)(q0 + r * 16 + lq)) * 2304 + h * 64 + g * 8;
        qb[r][0] = *(const s16x8*)qp;
        qb[r][1] = *(const s16x8*)(qp + 32);
    }

    const int srow = l >> 3;                    // 0..7
    const int scol = ((l & 7) ^ srow) * 8;      // pre-swizzled col (shorts)
    const short* kSrc = qkv + (size_t)(b * 1024 + w * 16 + srow) * 2304 + 768 + h * 64 + scol;
    const short* vSrc = vTg + (size_t)(bh * 64 + w * 16 + srow) * 1024 + scol;

    // prologue: stage kt=0 into buffer 0
    gload16(kSrc,                         &Ks[0][w * 1024]);
    gload16(kSrc + (size_t)8 * 2304,      &Ks[0][w * 1024 + 512]);
    gload16(vSrc,                         &Vs[0][w * 1024]);
    gload16(vSrc + (size_t)8 * 1024,      &Vs[0][w * 1024 + 512]);
    __syncthreads();

    f32x4 acc[2][4] = {};    // acc[r][dt][j] = O^T[d=dt*16+g*4+j][q=r*16+lq]
    float m_run[2] = {-1e30f, -1e30f};
    float l_run[2] = {0.f, 0.f};

    const int swz = (lq & 7) * 8;   // read-side XOR (shorts)

    int cur = 0;
    for (int kt = 0; kt < 16; kt++) {
        if (kt < 15) {
            const short* kS = kSrc + (size_t)(kt + 1) * 64 * 2304;
            const short* vS = vSrc + (kt + 1) * 64;
            gload16(kS,                    &Ks[cur ^ 1][w * 1024]);
            gload16(kS + (size_t)8 * 2304, &Ks[cur ^ 1][w * 1024 + 512]);
            gload16(vS,                    &Vs[cur ^ 1][w * 1024]);
            gload16(vS + (size_t)8 * 1024, &Vs[cur ^ 1][w * 1024 + 512]);
        }

        // A = K fragments from LDS
        s16x8 ka[4][2];
#pragma unroll
        for (int n = 0; n < 4; n++) {
            const int rbase = (n * 16 + lq) * 64;
            ka[n][0] = *(const s16x8*)&Ks[cur][rbase + ((g * 8) ^ swz)];
            ka[n][1] = *(const s16x8*)&Ks[cur][rbase + ((32 + g * 8) ^ swz)];
        }

        f32x4 s[2][4];
#pragma unroll
        for (int r = 0; r < 2; r++)
#pragma unroll
            for (int n = 0; n < 4; n++) {
                f32x4 sv = {};
                sv = __builtin_amdgcn_mfma_f32_16x16x32_bf16(ka[n][0], qb[r][0], sv, 0, 0, 0);
                sv = __builtin_amdgcn_mfma_f32_16x16x32_bf16(ka[n][1], qb[r][1], sv, 0, 0, 0);
                s[r][n] = sv;
            }

        // A = V^T fragments (issued before softmax to hide ds latency)
        s16x8 va[4][2];
#pragma unroll
        for (int dt = 0; dt < 4; dt++) {
            const int rbase = (dt * 16 + lq) * 64;
            va[dt][0] = *(const s16x8*)&Vs[cur][rbase + ((g * 8) ^ swz)];
            va[dt][1] = *(const s16x8*)&Vs[cur][rbase + ((32 + g * 8) ^ swz)];
        }

        // lane-local softmax with defer-max (THR=8 in log2 domain)
#pragma unroll
        for (int r = 0; r < 2; r++) {
            float mx = fmaxf(fmaxf(s[r][0][0], s[r][0][1]), fmaxf(s[r][0][2], s[r][0][3]));
#pragma unroll
            for (int n = 1; n < 4; n++)
                mx = fmaxf(mx, fmaxf(fmaxf(s[r][n][0], s[r][n][1]), fmaxf(s[r][n][2], s[r][n][3])));
            const float mxs = mx * kSc;
            if (!__all(mxs - m_run[r] <= 8.0f)) {
                float gm = mxs;
                gm = fmaxf(gm, __shfl_xor(gm, 16, 64));
                gm = fmaxf(gm, __shfl_xor(gm, 32, 64));
                const float mnew = fmaxf(m_run[r], gm);
                const float alpha = __builtin_amdgcn_exp2f(m_run[r] - mnew);
                m_run[r] = mnew;
                l_run[r] *= alpha;
#pragma unroll
                for (int dt = 0; dt < 4; dt++) {
                    acc[r][dt][0] *= alpha; acc[r][dt][1] *= alpha;
                    acc[r][dt][2] *= alpha; acc[r][dt][3] *= alpha;
                }
            }
            const float mb = m_run[r];
            float ssum = 0.f;
#pragma unroll
            for (int n = 0; n < 4; n++) {
                const float p0 = __builtin_amdgcn_exp2f(s[r][n][0] * kSc - mb);
                const float p1 = __builtin_amdgcn_exp2f(s[r][n][1] * kSc - mb);
                const float p2 = __builtin_amdgcn_exp2f(s[r][n][2] * kSc - mb);
                const float p3 = __builtin_amdgcn_exp2f(s[r][n][3] * kSc - mb);
                ssum += (p0 + p1) + (p2 + p3);
                unsigned lo, hi;
                asm("v_cvt_pk_bf16_f32 %0, %1, %2" : "=v"(lo) : "v"(p0), "v"(p1));
                asm("v_cvt_pk_bf16_f32 %0, %1, %2" : "=v"(hi) : "v"(p2), "v"(p3));
                unsigned* pp = (unsigned*)&Ps[w][r * 16 + lq][n * 16 + g * 4];
                pp[0] = lo; pp[1] = hi;
            }
            l_run[r] += ssum;
        }

        // O^T += V^T * P  (B = P from wave-private LDS; DS in-order per wave)
#pragma unroll
        for (int r = 0; r < 2; r++) {
            const s16x8 pb0 = *(const s16x8*)&Ps[w][r * 16 + lq][g * 8];
            const s16x8 pb1 = *(const s16x8*)&Ps[w][r * 16 + lq][32 + g * 8];
#pragma unroll
            for (int dt = 0; dt < 4; dt++) {
                acc[r][dt] = __builtin_amdgcn_mfma_f32_16x16x32_bf16(va[dt][0], pb0, acc[r][dt], 0, 0, 0);
                acc[r][dt] = __builtin_amdgcn_mfma_f32_16x16x32_bf16(va[dt][1], pb1, acc[r][dt], 0, 0, 0);
            }
        }

        __syncthreads();
        if (kt < 15) cur ^= 1;
    }

#pragma unroll
    for (int r = 0; r < 2; r++) {
        float ls = l_run[r];
        ls += __shfl_xor(ls, 16, 64);
        ls += __shfl_xor(ls, 32, 64);
        const float rinv = 1.0f / ls;
        const int qrow = q0 + r * 16 + lq;
#pragma unroll
        for (int dt = 0; dt < 4; dt++) {
            s16x4 ov;
#pragma unroll
            for (int j = 0; j < 4; j++) ov[j] = f2bf(acc[r][dt][j] * rinv);
            *(s16x4*)(out + (size_t)qrow * 768 + h * 64 + dt * 16 + g * 4) = ov;
        }
    }
}

extern "C" void kernel_launch(void* const* d_in, const int* in_sizes, int n_in,
                              void* d_out, int out_size, void* d_ws, size_t ws_size,
                              hipStream_t stream) {
    const float* x      = (const float*)d_in[0];
    const float* n1g    = (const float*)d_in[1];
    const float* n1b    = (const float*)d_in[2];
    const float* qkv_w  = (const float*)d_in[3];
    const float* qkv_b  = (const float*)d_in[4];
    const float* proj_w = (const float*)d_in[5];
    const float* proj_b = (const float*)d_in[6];
    const float* n2g    = (const float*)d_in[7];
    const float* n2b    = (const float*)d_in[8];
    const float* fc1_w  = (const float*)d_in[9];
    const float* fc1_b  = (const float*)d_in[10];
    const float* fc2_w  = (const float*)d_in[11];
    const float* fc2_b  = (const float*)d_in[12];
    float* out = (float*)d_out;

    char* ws = (char*)d_ws;
    short* qkv_wT  = (short*)(ws + 0);           // [2304][768] bf16
    short* proj_wT = (short*)(ws + 3538944);     // [768][768]
    short* fc1_wT  = (short*)(ws + 4718592);     // [3072][768]
    short* fc2_wT  = (short*)(ws + 9437184);     // [768][3072]
    short* bufA    = (short*)(ws + 14155776);    // 8192x768 bf16 (ln1/attn_out/ln2)
    short* bufB    = (short*)(ws + 26738688);    // 8192x3072 bf16 (qkv / h1)
    short* vT      = (short*)(ws + 64487424);    // 96x64x1024 bf16
    float* bufC    = (float*)(ws + 77070336);    // 8192x768 f32 (x1)

    const dim3 tb(32, 8);
    transpose_convert<<<dim3(2304 / 32, 768 / 32), tb, 0, stream>>>(qkv_w, qkv_wT, 768, 2304);
    transpose_convert<<<dim3(768 / 32, 768 / 32),  tb, 0, stream>>>(proj_w, proj_wT, 768, 768);
    transpose_convert<<<dim3(3072 / 32, 768 / 32), tb, 0, stream>>>(fc1_w, fc1_wT, 768, 3072);
    transpose_convert<<<dim3(768 / 32, 3072 / 32), tb, 0, stream>>>(fc2_w, fc2_wT, 3072, 768);

    layernorm_kernel<<<8192, 256, 0, stream>>>(x, n1g, n1b, bufA);

    gemm_bt<3><<<64 * (2304 / 128), 256, 0, stream>>>(
        bufA, qkv_wT, qkv_b, nullptr, bufB, vT, 8192, 2304, 768);

    attn_kernel<<<768, 256, 0, stream>>>(bufB, vT, bufA);

    gemm_bt<1><<<64 * (768 / 128), 256, 0, stream>>>(
        bufA, proj_wT, proj_b, x, bufC, nullptr, 8192, 768, 768);

    layernorm_kernel<<<8192, 256, 0, stream>>>(bufC, n2g, n2b, bufA);

    gemm_bt<2><<<64 * (3072 / 128), 256, 0, stream>>>(
        bufA, fc1_wT, fc1_b, nullptr, bufB, nullptr, 8192, 3072, 768);

    gemm_bt<1><<<64 * (768 / 128), 256, 0, stream>>>(
        bufB, fc2_wT, fc2_b, bufC, out, nullptr, 8192, 768, 3072);
}

// Round 11
// 257.596 us; speedup vs baseline: 1.7937x; 1.0867x over previous
//
#include <hip/hip_runtime.h>

typedef __attribute__((ext_vector_type(8))) short s16x8;
typedef __attribute__((ext_vector_type(4))) short s16x4;
typedef __attribute__((ext_vector_type(4))) float f32x4;

static __device__ __forceinline__ short f2bf(float f) {
    unsigned u = __builtin_bit_cast(unsigned, f);
    u = (u + 0x7FFFu + ((u >> 16) & 1u)) >> 16;
    return (short)u;
}

__device__ __forceinline__ void gload16(const short* g, short* l) {
    __builtin_amdgcn_global_load_lds(
        (const __attribute__((address_space(1))) void*)g,
        (__attribute__((address_space(3))) void*)l,
        16, 0, 0);
}

// ---------------- transpose + fp32->bf16 convert:  W[K][N] f32 -> Wt[N][K] bf16
__global__ __launch_bounds__(256) void transpose_convert(
    const float* __restrict__ W, short* __restrict__ Wt, int K, int N)
{
    __shared__ float tile[32][33];
    const int bx = blockIdx.x * 32;  // N
    const int by = blockIdx.y * 32;  // K
    const int tx = threadIdx.x;      // 0..31
    const int ty = threadIdx.y;      // 0..7
    for (int i = 0; i < 32; i += 8)
        tile[ty + i][tx] = W[(size_t)(by + ty + i) * N + bx + tx];
    __syncthreads();
    for (int i = 0; i < 32; i += 8)
        Wt[(size_t)(bx + ty + i) * K + by + tx] = f2bf(tile[tx][ty + i]);
}

// ---------------- LayerNorm: x[8192][768] f32 -> out bf16
__global__ __launch_bounds__(256) void layernorm_kernel(
    const float* __restrict__ x, const float* __restrict__ g,
    const float* __restrict__ b, short* __restrict__ out)
{
    const int row = blockIdx.x;
    const float* xr = x + (size_t)row * 768;
    const int t = threadIdx.x;
    float v0 = xr[t], v1 = xr[t + 256], v2 = xr[t + 512];
    __shared__ float red[4];

    float s = v0 + v1 + v2;
    for (int off = 32; off >= 1; off >>= 1) s += __shfl_down(s, off, 64);
    if ((t & 63) == 0) red[t >> 6] = s;
    __syncthreads();
    const float mean = (red[0] + red[1] + red[2] + red[3]) * (1.0f / 768.0f);
    const float d0 = v0 - mean, d1 = v1 - mean, d2 = v2 - mean;
    __syncthreads();
    float ss = d0 * d0 + d1 * d1 + d2 * d2;
    for (int off = 32; off >= 1; off >>= 1) ss += __shfl_down(ss, off, 64);
    if ((t & 63) == 0) red[t >> 6] = ss;
    __syncthreads();
    const float var = (red[0] + red[1] + red[2] + red[3]) * (1.0f / 768.0f);
    const float rstd = rsqrtf(var + 1e-5f);
    out[(size_t)row * 768 + t]       = f2bf(d0 * rstd * g[t] + b[t]);
    out[(size_t)row * 768 + t + 256] = f2bf(d1 * rstd * g[t + 256] + b[t + 256]);
    out[(size_t)row * 768 + t + 512] = f2bf(d2 * rstd * g[t + 512] + b[t + 512]);
}

// ---------------- GEMM v3: BK=64, templated BN (128 or 64), XOR-swizzled LDS,
// XCD-affine flat grid. C[M][N] = A * Bt^T + bias. M = 8192 (64 row-panels).
// MODE 0: out bf16 = acc + bias
// MODE 1: out f32  = acc + bias + res
// MODE 2: out bf16 = gelu_tanh(acc + bias)
// MODE 3: QKV: cols<1536 -> bf16 out; cols>=1536 (V) -> vtout[bh*64+d][n] s16x4
template <int MODE, int BN>
__global__ __launch_bounds__(256) void gemm_bt(
    const short* __restrict__ A, const short* __restrict__ Bt,
    const float* __restrict__ bias, const float* __restrict__ res,
    void* __restrict__ out, short* __restrict__ vtout, int M, int N, int K)
{
    constexpr int NF = BN / 32;   // n-fragments per wave (2x2 wave grid)
    __shared__ __align__(16) short As[128 * 64];
    __shared__ __align__(16) short Bs[BN * 64];

    const int t = threadIdx.x;
    const int l = t & 63;
    const int w = t >> 6;
    const int wr = (w >> 1) * 64;
    const int wc = (w & 1) * (BN / 2);

    const int ncol = N / BN;
    const int xcd = blockIdx.x & 7;
    const int idx = blockIdx.x >> 3;
    const int tn = (idx % ncol) * BN;
    const int tm = ((idx / ncol) * 8 + xcd) << 7;

    // staging chunks of (8 rows x 128B); pre-swizzled global source column so
    // a swizzled ds_read recovers true layout (swizzle both sides).
    const int srow = l >> 3;                  // 0..7 within chunk
    const int scol = ((l & 7) ^ srow) * 8;    // shorts
    const short* aS[4]; const short* bS[NF];
#pragma unroll
    for (int c = 0; c < 4; c++)
        aS[c] = A  + (size_t)(tm + (w * 4 + c) * 8 + srow) * K + scol;
#pragma unroll
    for (int c = 0; c < NF; c++)
        bS[c] = Bt + (size_t)(tn + (w * NF + c) * 8 + srow) * K + scol;

    const int fr = l & 15;
    const int g = l >> 4;
    const int sl = fr & 7;            // row component of the XOR swizzle

    f32x4 acc[4][NF] = {};

    for (int k0 = 0; k0 < K; k0 += 64) {
#pragma unroll
        for (int c = 0; c < 4; c++)
            gload16(aS[c] + k0, &As[(w * 4 + c) * 512]);
#pragma unroll
        for (int c = 0; c < NF; c++)
            gload16(bS[c] + k0, &Bs[(w * NF + c) * 512]);
        __syncthreads();   // drains vmcnt -> tiles complete

        s16x8 af[4][2], bf[NF][2];
#pragma unroll
        for (int m = 0; m < 4; m++) {
            const int rbase = (wr + m * 16 + fr) * 64;
            af[m][0] = *(const s16x8*)&As[rbase + ((g ^ sl) * 8)];
            af[m][1] = *(const s16x8*)&As[rbase + (((4 + g) ^ sl) * 8)];
        }
#pragma unroll
        for (int n = 0; n < NF; n++) {
            const int rbase = (wc + n * 16 + fr) * 64;
            bf[n][0] = *(const s16x8*)&Bs[rbase + ((g ^ sl) * 8)];
            bf[n][1] = *(const s16x8*)&Bs[rbase + (((4 + g) ^ sl) * 8)];
        }
#pragma unroll
        for (int m = 0; m < 4; m++)
#pragma unroll
            for (int n = 0; n < NF; n++) {
                acc[m][n] = __builtin_amdgcn_mfma_f32_16x16x32_bf16(af[m][0], bf[n][0], acc[m][n], 0, 0, 0);
                acc[m][n] = __builtin_amdgcn_mfma_f32_16x16x32_bf16(af[m][1], bf[n][1], acc[m][n], 0, 0, 0);
            }
        __syncthreads();   // protect LDS reuse next iter
    }

    const int fq = (l >> 4) * 4;
#pragma unroll
    for (int m = 0; m < 4; m++) {
#pragma unroll
        for (int n = 0; n < NF; n++) {
            const int col = tn + wc + n * 16 + fr;
            const float bv = bias[col];
            if (MODE == 3 && col >= 1536) {
                // V-part: write transposed directly, 4 consecutive n_seq -> 8B store
                const int row0 = tm + wr + m * 16 + fq;
                const int bb = row0 >> 10;
                const int nseq = row0 & 1023;
                s16x4 ov;
#pragma unroll
                for (int j = 0; j < 4; j++) ov[j] = f2bf(acc[m][n][j] + bv);
                *(s16x4*)(vtout + (((size_t)(bb * 768 + (col - 1536))) << 10) + nseq) = ov;
            } else {
#pragma unroll
                for (int j = 0; j < 4; j++) {
                    const int row = tm + wr + m * 16 + fq + j;
                    float v = acc[m][n][j] + bv;
                    if (MODE == 2) {
                        // gelu tanh-form via exp2: 0.5v(1+tanh(u)) = v - v/(e^{2u}+1)
                        const float u = v * (0.7978845608f + 0.0356774081f * v * v);
                        const float e = __builtin_amdgcn_exp2f(u * 2.8853900817779268f);
                        v = v - v * __builtin_amdgcn_rcpf(e + 1.0f);
                    }
                    if (MODE == 1) {
                        ((float*)out)[(size_t)row * N + col] = v + res[(size_t)row * N + col];
                    } else {
                        ((short*)out)[(size_t)row * N + col] = f2bf(v);
                    }
                }
            }
        }
    }
}

// ---------------- Flash attention v6: swapped QK^T/PV, lane-local softmax,
// defer-max (THR=8), cvt_pk P packing, LDS-staged K/Vt (double-buffered,
// XOR-swizzled both sides), XCD-affine mapping.
// grid: flat 768, block 256 (4 waves, each owns 32 q-rows).
__global__ __launch_bounds__(256) void attn_kernel(
    const short* __restrict__ qkv, const short* __restrict__ vTg,
    short* __restrict__ out)
{
    const int bid = blockIdx.x;
    const int x = bid & 7;
    const int i = bid >> 3;            // 0..95
    const int bh = x + 8 * (i % 12);   // 0..95
    const int qt = i / 12;             // 0..7
    const int b = bh / 12, h = bh % 12;

    __shared__ __align__(16) short Ks[2][64 * 64];
    __shared__ __align__(16) short Vs[2][64 * 64];
    __shared__ __align__(16) short Ps[4][32][72];

    const int t = threadIdx.x;
    const int l = t & 63;
    const int w = t >> 6;
    const int lq = l & 15;   // q-column / fragment row
    const int g = l >> 4;    // lane group 0..3
    const float kSc = 0.18033688011112042f;  // 0.125 * log2(e)

    const int q0 = b * 1024 + qt * 128 + w * 32;

    // Q as B-operand: lane holds Q[q=r*16+lq][d = g*8..+8 (+32)]
    s16x8 qb[2][2];
#pragma unroll
    for (int r = 0; r < 2; r++) {
        const short* qp = qkv + ((size_t)(q0 + r * 16 + lq)) * 2304 + h * 64 + g * 8;
        qb[r][0] = *(const s16x8*)qp;
        qb[r][1] = *(const s16x8*)(qp + 32);
    }

    const int srow = l >> 3;                    // 0..7
    const int scol = ((l & 7) ^ srow) * 8;      // pre-swizzled col (shorts)
    const short* kSrc = qkv + (size_t)(b * 1024 + w * 16 + srow) * 2304 + 768 + h * 64 + scol;
    const short* vSrc = vTg + (size_t)(bh * 64 + w * 16 + srow) * 1024 + scol;

    // prologue: stage kt=0 into buffer 0
    gload16(kSrc,                         &Ks[0][w * 1024]);
    gload16(kSrc + (size_t)8 * 2304,      &Ks[0][w * 1024 + 512]);
    gload16(vSrc,                         &Vs[0][w * 1024]);
    gload16(vSrc + (size_t)8 * 1024,      &Vs[0][w * 1024 + 512]);
    __syncthreads();

    f32x4 acc[2][4] = {};    // acc[r][dt][j] = O^T[d=dt*16+g*4+j][q=r*16+lq]
    float m_run[2] = {-1e30f, -1e30f};
    float l_run[2] = {0.f, 0.f};

    const int swz = (lq & 7) * 8;   // read-side XOR (shorts)

    int cur = 0;
    for (int kt = 0; kt < 16; kt++) {
        if (kt < 15) {
            const short* kS = kSrc + (size_t)(kt + 1) * 64 * 2304;
            const short* vS = vSrc + (kt + 1) * 64;
            gload16(kS,                    &Ks[cur ^ 1][w * 1024]);
            gload16(kS + (size_t)8 * 2304, &Ks[cur ^ 1][w * 1024 + 512]);
            gload16(vS,                    &Vs[cur ^ 1][w * 1024]);
            gload16(vS + (size_t)8 * 1024, &Vs[cur ^ 1][w * 1024 + 512]);
        }

        // A = K fragments from LDS
        s16x8 ka[4][2];
#pragma unroll
        for (int n = 0; n < 4; n++) {
            const int rbase = (n * 16 + lq) * 64;
            ka[n][0] = *(const s16x8*)&Ks[cur][rbase + ((g * 8) ^ swz)];
            ka[n][1] = *(const s16x8*)&Ks[cur][rbase + ((32 + g * 8) ^ swz)];
        }

        f32x4 s[2][4];
#pragma unroll
        for (int r = 0; r < 2; r++)
#pragma unroll
            for (int n = 0; n < 4; n++) {
                f32x4 sv = {};
                sv = __builtin_amdgcn_mfma_f32_16x16x32_bf16(ka[n][0], qb[r][0], sv, 0, 0, 0);
                sv = __builtin_amdgcn_mfma_f32_16x16x32_bf16(ka[n][1], qb[r][1], sv, 0, 0, 0);
                s[r][n] = sv;
            }

        // A = V^T fragments (issued before softmax to hide ds latency)
        s16x8 va[4][2];
#pragma unroll
        for (int dt = 0; dt < 4; dt++) {
            const int rbase = (dt * 16 + lq) * 64;
            va[dt][0] = *(const s16x8*)&Vs[cur][rbase + ((g * 8) ^ swz)];
            va[dt][1] = *(const s16x8*)&Vs[cur][rbase + ((32 + g * 8) ^ swz)];
        }

        // lane-local softmax with defer-max (THR=8 in log2 domain)
#pragma unroll
        for (int r = 0; r < 2; r++) {
            float mx = fmaxf(fmaxf(s[r][0][0], s[r][0][1]), fmaxf(s[r][0][2], s[r][0][3]));
#pragma unroll
            for (int n = 1; n < 4; n++)
                mx = fmaxf(mx, fmaxf(fmaxf(s[r][n][0], s[r][n][1]), fmaxf(s[r][n][2], s[r][n][3])));
            const float mxs = mx * kSc;
            if (!__all(mxs - m_run[r] <= 8.0f)) {
                float gm = mxs;
                gm = fmaxf(gm, __shfl_xor(gm, 16, 64));
                gm = fmaxf(gm, __shfl_xor(gm, 32, 64));
                const float mnew = fmaxf(m_run[r], gm);
                const float alpha = __builtin_amdgcn_exp2f(m_run[r] - mnew);
                m_run[r] = mnew;
                l_run[r] *= alpha;
#pragma unroll
                for (int dt = 0; dt < 4; dt++) {
                    acc[r][dt][0] *= alpha; acc[r][dt][1] *= alpha;
                    acc[r][dt][2] *= alpha; acc[r][dt][3] *= alpha;
                }
            }
            const float mb = m_run[r];
            float ssum = 0.f;
#pragma unroll
            for (int n = 0; n < 4; n++) {
                const float p0 = __builtin_amdgcn_exp2f(s[r][n][0] * kSc - mb);
                const float p1 = __builtin_amdgcn_exp2f(s[r][n][1] * kSc - mb);
                const float p2 = __builtin_amdgcn_exp2f(s[r][n][2] * kSc - mb);
                const float p3 = __builtin_amdgcn_exp2f(s[r][n][3] * kSc - mb);
                ssum += (p0 + p1) + (p2 + p3);
                unsigned lo, hi;
                asm("v_cvt_pk_bf16_f32 %0, %1, %2" : "=v"(lo) : "v"(p0), "v"(p1));
                asm("v_cvt_pk_bf16_f32 %0, %1, %2" : "=v"(hi) : "v"(p2), "v"(p3));
                unsigned* pp = (unsigned*)&Ps[w][r * 16 + lq][n * 16 + g * 4];
                pp[0] = lo; pp[1] = hi;
            }
            l_run[r] += ssum;
        }

        // O^T += V^T * P  (B = P from wave-private LDS; DS in-order per wave)
#pragma unroll
        for (int r = 0; r < 2; r++) {
            const s16x8 pb0 = *(const s16x8*)&Ps[w][r * 16 + lq][g * 8];
            const s16x8 pb1 = *(const s16x8*)&Ps[w][r * 16 + lq][32 + g * 8];
#pragma unroll
            for (int dt = 0; dt < 4; dt++) {
                acc[r][dt] = __builtin_amdgcn_mfma_f32_16x16x32_bf16(va[dt][0], pb0, acc[r][dt], 0, 0, 0);
                acc[r][dt] = __builtin_amdgcn_mfma_f32_16x16x32_bf16(va[dt][1], pb1, acc[r][dt], 0, 0, 0);
            }
        }

        __syncthreads();
        if (kt < 15) cur ^= 1;
    }

#pragma unroll
    for (int r = 0; r < 2; r++) {
        float ls = l_run[r];
        ls += __shfl_xor(ls, 16, 64);
        ls += __shfl_xor(ls, 32, 64);
        const float rinv = 1.0f / ls;
        const int qrow = q0 + r * 16 + lq;
#pragma unroll
        for (int dt = 0; dt < 4; dt++) {
            s16x4 ov;
#pragma unroll
            for (int j = 0; j < 4; j++) ov[j] = f2bf(acc[r][dt][j] * rinv);
            *(s16x4*)(out + (size_t)qrow * 768 + h * 64 + dt * 16 + g * 4) = ov;
        }
    }
}

extern "C" void kernel_launch(void* const* d_in, const int* in_sizes, int n_in,
                              void* d_out, int out_size, void* d_ws, size_t ws_size,
                              hipStream_t stream) {
    const float* x      = (const float*)d_in[0];
    const float* n1g    = (const float*)d_in[1];
    const float* n1b    = (const float*)d_in[2];
    const float* qkv_w  = (const float*)d_in[3];
    const float* qkv_b  = (const float*)d_in[4];
    const float* proj_w = (const float*)d_in[5];
    const float* proj_b = (const float*)d_in[6];
    const float* n2g    = (const float*)d_in[7];
    const float* n2b    = (const float*)d_in[8];
    const float* fc1_w  = (const float*)d_in[9];
    const float* fc1_b  = (const float*)d_in[10];
    const float* fc2_w  = (const float*)d_in[11];
    const float* fc2_b  = (const float*)d_in[12];
    float* out = (float*)d_out;

    char* ws = (char*)d_ws;
    short* qkv_wT  = (short*)(ws + 0);           // [2304][768] bf16
    short* proj_wT = (short*)(ws + 3538944);     // [768][768]
    short* fc1_wT  = (short*)(ws + 4718592);     // [3072][768]
    short* fc2_wT  = (short*)(ws + 9437184);     // [768][3072]
    short* bufA    = (short*)(ws + 14155776);    // 8192x768 bf16 (ln1/attn_out/ln2)
    short* bufB    = (short*)(ws + 26738688);    // 8192x3072 bf16 (qkv / h1)
    short* vT      = (short*)(ws + 64487424);    // 96x64x1024 bf16
    float* bufC    = (float*)(ws + 77070336);    // 8192x768 f32 (x1)

    const dim3 tb(32, 8);
    transpose_convert<<<dim3(2304 / 32, 768 / 32), tb, 0, stream>>>(qkv_w, qkv_wT, 768, 2304);
    transpose_convert<<<dim3(768 / 32, 768 / 32),  tb, 0, stream>>>(proj_w, proj_wT, 768, 768);
    transpose_convert<<<dim3(3072 / 32, 768 / 32), tb, 0, stream>>>(fc1_w, fc1_wT, 768, 3072);
    transpose_convert<<<dim3(768 / 32, 3072 / 32), tb, 0, stream>>>(fc2_w, fc2_wT, 3072, 768);

    layernorm_kernel<<<8192, 256, 0, stream>>>(x, n1g, n1b, bufA);

    gemm_bt<3, 128><<<64 * (2304 / 128), 256, 0, stream>>>(
        bufA, qkv_wT, qkv_b, nullptr, bufB, vT, 8192, 2304, 768);

    attn_kernel<<<768, 256, 0, stream>>>(bufB, vT, bufA);

    gemm_bt<1, 64><<<64 * (768 / 64), 256, 0, stream>>>(
        bufA, proj_wT, proj_b, x, bufC, nullptr, 8192, 768, 768);

    layernorm_kernel<<<8192, 256, 0, stream>>>(bufC, n2g, n2b, bufA);

    gemm_bt<2, 128><<<64 * (3072 / 128), 256, 0, stream>>>(
        bufA, fc1_wT, fc1_b, nullptr, bufB, nullptr, 8192, 3072, 768);

    gemm_bt<1, 64><<<64 * (768 / 64), 256, 0, stream>>>(
        bufB, fc2_wT, fc2_b, bufC, out, nullptr, 8192, 768, 3072);
}

// Round 12
// 244.854 us; speedup vs baseline: 1.8870x; 1.0520x over previous
//
#include <hip/hip_runtime.h>

typedef __attribute__((ext_vector_type(8))) short s16x8;
typedef __attribute__((ext_vector_type(4))) short s16x4;
typedef __attribute__((ext_vector_type(4))) float f32x4;

static __device__ __forceinline__ short f2bf(float f) {
    unsigned u = __builtin_bit_cast(unsigned, f);
    u = (u + 0x7FFFu + ((u >> 16) & 1u)) >> 16;
    return (short)u;
}

__device__ __forceinline__ void gload16(const short* g, short* l) {
    __builtin_amdgcn_global_load_lds(
        (const __attribute__((address_space(1))) void*)g,
        (__attribute__((address_space(3))) void*)l,
        16, 0, 0);
}

// ---------------- transpose + fp32->bf16 convert:  W[K][N] f32 -> Wt[N][K] bf16
__global__ __launch_bounds__(256) void transpose_convert(
    const float* __restrict__ W, short* __restrict__ Wt, int K, int N)
{
    __shared__ float tile[32][33];
    const int bx = blockIdx.x * 32;  // N
    const int by = blockIdx.y * 32;  // K
    const int tx = threadIdx.x;      // 0..31
    const int ty = threadIdx.y;      // 0..7
    for (int i = 0; i < 32; i += 8)
        tile[ty + i][tx] = W[(size_t)(by + ty + i) * N + bx + tx];
    __syncthreads();
    for (int i = 0; i < 32; i += 8)
        Wt[(size_t)(bx + ty + i) * K + by + tx] = f2bf(tile[tx][ty + i]);
}

// ---------------- LayerNorm: x[8192][768] f32 -> out bf16
__global__ __launch_bounds__(256) void layernorm_kernel(
    const float* __restrict__ x, const float* __restrict__ g,
    const float* __restrict__ b, short* __restrict__ out)
{
    const int row = blockIdx.x;
    const float* xr = x + (size_t)row * 768;
    const int t = threadIdx.x;
    float v0 = xr[t], v1 = xr[t + 256], v2 = xr[t + 512];
    __shared__ float red[4];

    float s = v0 + v1 + v2;
    for (int off = 32; off >= 1; off >>= 1) s += __shfl_down(s, off, 64);
    if ((t & 63) == 0) red[t >> 6] = s;
    __syncthreads();
    const float mean = (red[0] + red[1] + red[2] + red[3]) * (1.0f / 768.0f);
    const float d0 = v0 - mean, d1 = v1 - mean, d2 = v2 - mean;
    __syncthreads();
    float ss = d0 * d0 + d1 * d1 + d2 * d2;
    for (int off = 32; off >= 1; off >>= 1) ss += __shfl_down(ss, off, 64);
    if ((t & 63) == 0) red[t >> 6] = ss;
    __syncthreads();
    const float var = (red[0] + red[1] + red[2] + red[3]) * (1.0f / 768.0f);
    const float rstd = rsqrtf(var + 1e-5f);
    out[(size_t)row * 768 + t]       = f2bf(d0 * rstd * g[t] + b[t]);
    out[(size_t)row * 768 + t + 256] = f2bf(d1 * rstd * g[t + 256] + b[t + 256]);
    out[(size_t)row * 768 + t + 512] = f2bf(d2 * rstd * g[t + 512] + b[t + 512]);
}

// ---------------- GEMM v3 (single-buffered, BN=128): BK=64, XOR-swizzled LDS,
// XCD-affine flat grid. C = A * Bt^T + bias. M = 8192.
// MODE 2: out bf16 = gelu_tanh(acc + bias)
// MODE 3: QKV: cols<1536 -> bf16 out; cols>=1536 (V) -> vtout[bh*64+d][n] s16x4
template <int MODE>
__global__ __launch_bounds__(256) void gemm_bt(
    const short* __restrict__ A, const short* __restrict__ Bt,
    const float* __restrict__ bias, const float* __restrict__ res,
    void* __restrict__ out, short* __restrict__ vtout, int M, int N, int K)
{
    __shared__ __align__(16) short As[128 * 64];
    __shared__ __align__(16) short Bs[128 * 64];

    const int t = threadIdx.x;
    const int l = t & 63;
    const int w = t >> 6;
    const int wr = (w >> 1) * 64;
    const int wc = (w & 1) * 64;

    const int ncol = N >> 7;
    const int xcd = blockIdx.x & 7;
    const int idx = blockIdx.x >> 3;
    const int tn = (idx % ncol) << 7;
    const int tm = ((idx / ncol) * 8 + xcd) << 7;

    const int srow = l >> 3;                  // 0..7 within chunk
    const int scol = ((l & 7) ^ srow) * 8;    // pre-swizzled col (shorts)
    const short* aS[4]; const short* bS[4];
#pragma unroll
    for (int c = 0; c < 4; c++) {
        aS[c] = A  + (size_t)(tm + (w * 4 + c) * 8 + srow) * K + scol;
        bS[c] = Bt + (size_t)(tn + (w * 4 + c) * 8 + srow) * K + scol;
    }

    const int fr = l & 15;
    const int g = l >> 4;
    const int sl = fr & 7;            // row component of the XOR swizzle

    f32x4 acc[4][4] = {};

    for (int k0 = 0; k0 < K; k0 += 64) {
#pragma unroll
        for (int c = 0; c < 4; c++) {
            gload16(aS[c] + k0, &As[(w * 4 + c) * 512]);
            gload16(bS[c] + k0, &Bs[(w * 4 + c) * 512]);
        }
        __syncthreads();

        s16x8 af[4][2], bf[4][2];
#pragma unroll
        for (int m = 0; m < 4; m++) {
            const int rbase = (wr + m * 16 + fr) * 64;
            af[m][0] = *(const s16x8*)&As[rbase + ((g ^ sl) * 8)];
            af[m][1] = *(const s16x8*)&As[rbase + (((4 + g) ^ sl) * 8)];
        }
#pragma unroll
        for (int n = 0; n < 4; n++) {
            const int rbase = (wc + n * 16 + fr) * 64;
            bf[n][0] = *(const s16x8*)&Bs[rbase + ((g ^ sl) * 8)];
            bf[n][1] = *(const s16x8*)&Bs[rbase + (((4 + g) ^ sl) * 8)];
        }
#pragma unroll
        for (int m = 0; m < 4; m++)
#pragma unroll
            for (int n = 0; n < 4; n++) {
                acc[m][n] = __builtin_amdgcn_mfma_f32_16x16x32_bf16(af[m][0], bf[n][0], acc[m][n], 0, 0, 0);
                acc[m][n] = __builtin_amdgcn_mfma_f32_16x16x32_bf16(af[m][1], bf[n][1], acc[m][n], 0, 0, 0);
            }
        __syncthreads();
    }

    const int fq = (l >> 4) * 4;
#pragma unroll
    for (int m = 0; m < 4; m++) {
#pragma unroll
        for (int n = 0; n < 4; n++) {
            const int col = tn + wc + n * 16 + fr;
            const float bv = bias[col];
            if (MODE == 3 && col >= 1536) {
                const int row0 = tm + wr + m * 16 + fq;
                const int bb = row0 >> 10;
                const int nseq = row0 & 1023;
                s16x4 ov;
#pragma unroll
                for (int j = 0; j < 4; j++) ov[j] = f2bf(acc[m][n][j] + bv);
                *(s16x4*)(vtout + (((size_t)(bb * 768 + (col - 1536))) << 10) + nseq) = ov;
            } else {
#pragma unroll
                for (int j = 0; j < 4; j++) {
                    const int row = tm + wr + m * 16 + fq + j;
                    float v = acc[m][n][j] + bv;
                    if (MODE == 2) {
                        const float u = v * (0.7978845608f + 0.0356774081f * v * v);
                        const float e = __builtin_amdgcn_exp2f(u * 2.8853900817779268f);
                        v = v - v * __builtin_amdgcn_rcpf(e + 1.0f);
                    }
                    ((short*)out)[(size_t)row * N + col] = f2bf(v);
                }
            }
        }
    }
}

// ---------------- GEMM v4 (double-buffered 2-phase, BN=64, MODE 1):
// out f32 = acc + bias + res. Static buffers, prefetch-before-compute,
// one barrier per K-step. LDS 48KB, grid = 64*(N/64) = 3 blocks/CU exactly.
#define G_STAGE(AS, BS)                                                     \
    {                                                                       \
        _Pragma("unroll") for (int c = 0; c < 4; c++) {                     \
            gload16(aP[c], &AS[(w * 4 + c) * 512]); aP[c] += 64;            \
        }                                                                   \
        _Pragma("unroll") for (int c = 0; c < 2; c++) {                     \
            gload16(bP[c], &BS[(w * 2 + c) * 512]); bP[c] += 64;            \
        }                                                                   \
    }

#define G_COMPUTE(AS, BS)                                                   \
    {                                                                       \
        s16x8 af[4][2], bf[2][2];                                           \
        _Pragma("unroll") for (int m = 0; m < 4; m++) {                     \
            const int rbase = (wr + m * 16 + fr) * 64;                      \
            af[m][0] = *(const s16x8*)&AS[rbase + ((g ^ sl) * 8)];          \
            af[m][1] = *(const s16x8*)&AS[rbase + (((4 + g) ^ sl) * 8)];    \
        }                                                                   \
        _Pragma("unroll") for (int n = 0; n < 2; n++) {                     \
            const int rbase = (wc + n * 16 + fr) * 64;                      \
            bf[n][0] = *(const s16x8*)&BS[rbase + ((g ^ sl) * 8)];          \
            bf[n][1] = *(const s16x8*)&BS[rbase + (((4 + g) ^ sl) * 8)];    \
        }                                                                   \
        _Pragma("unroll") for (int m = 0; m < 4; m++)                       \
            _Pragma("unroll") for (int n = 0; n < 2; n++) {                 \
                acc[m][n] = __builtin_amdgcn_mfma_f32_16x16x32_bf16(af[m][0], bf[n][0], acc[m][n], 0, 0, 0); \
                acc[m][n] = __builtin_amdgcn_mfma_f32_16x16x32_bf16(af[m][1], bf[n][1], acc[m][n], 0, 0, 0); \
            }                                                               \
    }

__global__ __launch_bounds__(256) void gemm_bt_db(
    const short* __restrict__ A, const short* __restrict__ Bt,
    const float* __restrict__ bias, const float* __restrict__ res,
    float* __restrict__ out, int M, int N, int K)
{
    __shared__ __align__(16) short As0[128 * 64];
    __shared__ __align__(16) short As1[128 * 64];
    __shared__ __align__(16) short Bs0[64 * 64];
    __shared__ __align__(16) short Bs1[64 * 64];

    const int t = threadIdx.x;
    const int l = t & 63;
    const int w = t >> 6;
    const int wr = (w >> 1) * 64;
    const int wc = (w & 1) * 32;

    const int ncol = N >> 6;
    const int xcd = blockIdx.x & 7;
    const int idx = blockIdx.x >> 3;
    const int tn = (idx % ncol) << 6;
    const int tm = ((idx / ncol) * 8 + xcd) << 7;

    const int srow = l >> 3;
    const int scol = ((l & 7) ^ srow) * 8;
    const short* aP[4]; const short* bP[2];
#pragma unroll
    for (int c = 0; c < 4; c++)
        aP[c] = A  + (size_t)(tm + (w * 4 + c) * 8 + srow) * K + scol;
#pragma unroll
    for (int c = 0; c < 2; c++)
        bP[c] = Bt + (size_t)(tn + (w * 2 + c) * 8 + srow) * K + scol;

    const int fr = l & 15;
    const int g = l >> 4;
    const int sl = fr & 7;

    f32x4 acc[4][2] = {};

    G_STAGE(As0, Bs0);
    __syncthreads();

    const int half = K >> 7;   // iterations of two 64-steps
    for (int it = 0; it < half; ++it) {
        G_STAGE(As1, Bs1);          // prefetch step 2it+1
        G_COMPUTE(As0, Bs0);        // compute step 2it
        __syncthreads();
        if (it < half - 1) G_STAGE(As0, Bs0);   // prefetch step 2it+2
        G_COMPUTE(As1, Bs1);        // compute step 2it+1
        __syncthreads();
    }

    const int fq = g * 4;
#pragma unroll
    for (int m = 0; m < 4; m++) {
#pragma unroll
        for (int n = 0; n < 2; n++) {
            const int col = tn + wc + n * 16 + fr;
            const float bv = bias[col];
#pragma unroll
            for (int j = 0; j < 4; j++) {
                const int row = tm + wr + m * 16 + fq + j;
                out[(size_t)row * N + col] = acc[m][n][j] + bv + res[(size_t)row * N + col];
            }
        }
    }
}

// ---------------- Flash attention v7: swapped QK^T/PV, lane-local softmax,
// defer-max, cvt_pk packing, statically double-buffered K/Vt (kt unrolled x2,
// incremental source pointers), XOR-swizzled both sides, XCD-affine mapping.
// grid: flat 768, block 256 (4 waves, each owns 32 q-rows).
#define ATTN_STAGE(KS, VS)                                                  \
    {                                                                       \
        gload16(kP,                    &KS[w * 1024]);                      \
        gload16(kP + (size_t)8 * 2304, &KS[w * 1024 + 512]);                \
        gload16(vP,                    &VS[w * 1024]);                      \
        gload16(vP + (size_t)8 * 1024, &VS[w * 1024 + 512]);                \
        kP += (size_t)64 * 2304;                                            \
        vP += 64;                                                           \
    }

#define ATTN_COMPUTE(KS, VS)                                                \
    {                                                                       \
        s16x8 ka[4][2];                                                     \
        _Pragma("unroll") for (int n = 0; n < 4; n++) {                     \
            const int rbase = (n * 16 + lq) * 64;                           \
            ka[n][0] = *(const s16x8*)&KS[rbase + ((g * 8) ^ swz)];         \
            ka[n][1] = *(const s16x8*)&KS[rbase + ((32 + g * 8) ^ swz)];    \
        }                                                                   \
        f32x4 s[2][4];                                                      \
        _Pragma("unroll") for (int r = 0; r < 2; r++)                       \
            _Pragma("unroll") for (int n = 0; n < 4; n++) {                 \
                f32x4 sv = {};                                              \
                sv = __builtin_amdgcn_mfma_f32_16x16x32_bf16(ka[n][0], qb[r][0], sv, 0, 0, 0); \
                sv = __builtin_amdgcn_mfma_f32_16x16x32_bf16(ka[n][1], qb[r][1], sv, 0, 0, 0); \
                s[r][n] = sv;                                               \
            }                                                               \
        s16x8 va[4][2];                                                     \
        _Pragma("unroll") for (int dt = 0; dt < 4; dt++) {                  \
            const int rbase = (dt * 16 + lq) * 64;                          \
            va[dt][0] = *(const s16x8*)&VS[rbase + ((g * 8) ^ swz)];        \
            va[dt][1] = *(const s16x8*)&VS[rbase + ((32 + g * 8) ^ swz)];   \
        }                                                                   \
        _Pragma("unroll") for (int r = 0; r < 2; r++) {                     \
            float mx = fmaxf(fmaxf(s[r][0][0], s[r][0][1]), fmaxf(s[r][0][2], s[r][0][3])); \
            _Pragma("unroll") for (int n = 1; n < 4; n++)                   \
                mx = fmaxf(mx, fmaxf(fmaxf(s[r][n][0], s[r][n][1]), fmaxf(s[r][n][2], s[r][n][3]))); \
            const float mxs = mx * kSc;                                     \
            if (!__all(mxs - m_run[r] <= 8.0f)) {                           \
                float gm = mxs;                                             \
                gm = fmaxf(gm, __shfl_xor(gm, 16, 64));                     \
                gm = fmaxf(gm, __shfl_xor(gm, 32, 64));                     \
                const float mnew = fmaxf(m_run[r], gm);                     \
                const float alpha = __builtin_amdgcn_exp2f(m_run[r] - mnew);\
                m_run[r] = mnew;                                            \
                l_run[r] *= alpha;                                          \
                _Pragma("unroll") for (int dt = 0; dt < 4; dt++) {          \
                    acc[r][dt][0] *= alpha; acc[r][dt][1] *= alpha;         \
                    acc[r][dt][2] *= alpha; acc[r][dt][3] *= alpha;         \
                }                                                           \
            }                                                               \
            const float mb = m_run[r];                                      \
            float ssum = 0.f;                                               \
            _Pragma("unroll") for (int n = 0; n < 4; n++) {                 \
                const float p0 = __builtin_amdgcn_exp2f(s[r][n][0] * kSc - mb); \
                const float p1 = __builtin_amdgcn_exp2f(s[r][n][1] * kSc - mb); \
                const float p2 = __builtin_amdgcn_exp2f(s[r][n][2] * kSc - mb); \
                const float p3 = __builtin_amdgcn_exp2f(s[r][n][3] * kSc - mb); \
                ssum += (p0 + p1) + (p2 + p3);                              \
                unsigned lo, hi;                                            \
                asm("v_cvt_pk_bf16_f32 %0, %1, %2" : "=v"(lo) : "v"(p0), "v"(p1)); \
                asm("v_cvt_pk_bf16_f32 %0, %1, %2" : "=v"(hi) : "v"(p2), "v"(p3)); \
                unsigned* pp = (unsigned*)&Ps[w][r * 16 + lq][n * 16 + g * 4]; \
                pp[0] = lo; pp[1] = hi;                                     \
            }                                                               \
            l_run[r] += ssum;                                               \
        }                                                                   \
        _Pragma("unroll") for (int r = 0; r < 2; r++) {                     \
            const s16x8 pb0 = *(const s16x8*)&Ps[w][r * 16 + lq][g * 8];    \
            const s16x8 pb1 = *(const s16x8*)&Ps[w][r * 16 + lq][32 + g * 8]; \
            _Pragma("unroll") for (int dt = 0; dt < 4; dt++) {              \
                acc[r][dt] = __builtin_amdgcn_mfma_f32_16x16x32_bf16(va[dt][0], pb0, acc[r][dt], 0, 0, 0); \
                acc[r][dt] = __builtin_amdgcn_mfma_f32_16x16x32_bf16(va[dt][1], pb1, acc[r][dt], 0, 0, 0); \
            }                                                               \
        }                                                                   \
    }

__global__ __launch_bounds__(256) void attn_kernel(
    const short* __restrict__ qkv, const short* __restrict__ vTg,
    short* __restrict__ out)
{
    const int bid = blockIdx.x;
    const int x = bid & 7;
    const int i = bid >> 3;            // 0..95
    const int bh = x + 8 * (i % 12);   // 0..95
    const int qt = i / 12;             // 0..7
    const int b = bh / 12, h = bh % 12;

    __shared__ __align__(16) short Ks0[64 * 64];
    __shared__ __align__(16) short Ks1[64 * 64];
    __shared__ __align__(16) short Vs0[64 * 64];
    __shared__ __align__(16) short Vs1[64 * 64];
    __shared__ __align__(16) short Ps[4][32][72];

    const int t = threadIdx.x;
    const int l = t & 63;
    const int w = t >> 6;
    const int lq = l & 15;   // q-column / fragment row
    const int g = l >> 4;    // lane group 0..3
    const float kSc = 0.18033688011112042f;  // 0.125 * log2(e)

    const int q0 = b * 1024 + qt * 128 + w * 32;

    // Q as B-operand: lane holds Q[q=r*16+lq][d = g*8..+8 (+32)]
    s16x8 qb[2][2];
#pragma unroll
    for (int r = 0; r < 2; r++) {
        const short* qp = qkv + ((size_t)(q0 + r * 16 + lq)) * 2304 + h * 64 + g * 8;
        qb[r][0] = *(const s16x8*)qp;
        qb[r][1] = *(const s16x8*)(qp + 32);
    }

    const int srow = l >> 3;                    // 0..7
    const int scol = ((l & 7) ^ srow) * 8;      // pre-swizzled col (shorts)
    const short* kP = qkv + (size_t)(b * 1024 + w * 16 + srow) * 2304 + 768 + h * 64 + scol;
    const short* vP = vTg + (size_t)(bh * 64 + w * 16 + srow) * 1024 + scol;

    f32x4 acc[2][4] = {};    // acc[r][dt][j] = O^T[d=dt*16+g*4+j][q=r*16+lq]
    float m_run[2] = {-1e30f, -1e30f};
    float l_run[2] = {0.f, 0.f};

    const int swz = (lq & 7) * 8;   // read-side XOR (shorts)

    ATTN_STAGE(Ks0, Vs0);           // tile 0
    __syncthreads();

    for (int it = 0; it < 8; ++it) {
        ATTN_STAGE(Ks1, Vs1);       // tile 2it+1
        ATTN_COMPUTE(Ks0, Vs0);     // tile 2it
        __syncthreads();
        if (it < 7) ATTN_STAGE(Ks0, Vs0);   // tile 2it+2
        ATTN_COMPUTE(Ks1, Vs1);     // tile 2it+1
        __syncthreads();
    }

#pragma unroll
    for (int r = 0; r < 2; r++) {
        float ls = l_run[r];
        ls += __shfl_xor(ls, 16, 64);
        ls += __shfl_xor(ls, 32, 64);
        const float rinv = 1.0f / ls;
        const int qrow = q0 + r * 16 + lq;
#pragma unroll
        for (int dt = 0; dt < 4; dt++) {
            s16x4 ov;
#pragma unroll
            for (int j = 0; j < 4; j++) ov[j] = f2bf(acc[r][dt][j] * rinv);
            *(s16x4*)(out + (size_t)qrow * 768 + h * 64 + dt * 16 + g * 4) = ov;
        }
    }
}

extern "C" void kernel_launch(void* const* d_in, const int* in_sizes, int n_in,
                              void* d_out, int out_size, void* d_ws, size_t ws_size,
                              hipStream_t stream) {
    const float* x      = (const float*)d_in[0];
    const float* n1g    = (const float*)d_in[1];
    const float* n1b    = (const float*)d_in[2];
    const float* qkv_w  = (const float*)d_in[3];
    const float* qkv_b  = (const float*)d_in[4];
    const float* proj_w = (const float*)d_in[5];
    const float* proj_b = (const float*)d_in[6];
    const float* n2g    = (const float*)d_in[7];
    const float* n2b    = (const float*)d_in[8];
    const float* fc1_w  = (const float*)d_in[9];
    const float* fc1_b  = (const float*)d_in[10];
    const float* fc2_w  = (const float*)d_in[11];
    const float* fc2_b  = (const float*)d_in[12];
    float* out = (float*)d_out;

    char* ws = (char*)d_ws;
    short* qkv_wT  = (short*)(ws + 0);           // [2304][768] bf16
    short* proj_wT = (short*)(ws + 3538944);     // [768][768]
    short* fc1_wT  = (short*)(ws + 4718592);     // [3072][768]
    short* fc2_wT  = (short*)(ws + 9437184);     // [768][3072]
    short* bufA    = (short*)(ws + 14155776);    // 8192x768 bf16 (ln1/attn_out/ln2)
    short* bufB    = (short*)(ws + 26738688);    // 8192x3072 bf16 (qkv / h1)
    short* vT      = (short*)(ws + 64487424);    // 96x64x1024 bf16
    float* bufC    = (float*)(ws + 77070336);    // 8192x768 f32 (x1)

    const dim3 tb(32, 8);
    transpose_convert<<<dim3(2304 / 32, 768 / 32), tb, 0, stream>>>(qkv_w, qkv_wT, 768, 2304);
    transpose_convert<<<dim3(768 / 32, 768 / 32),  tb, 0, stream>>>(proj_w, proj_wT, 768, 768);
    transpose_convert<<<dim3(3072 / 32, 768 / 32), tb, 0, stream>>>(fc1_w, fc1_wT, 768, 3072);
    transpose_convert<<<dim3(768 / 32, 3072 / 32), tb, 0, stream>>>(fc2_w, fc2_wT, 3072, 768);

    layernorm_kernel<<<8192, 256, 0, stream>>>(x, n1g, n1b, bufA);

    gemm_bt<3><<<64 * (2304 / 128), 256, 0, stream>>>(
        bufA, qkv_wT, qkv_b, nullptr, bufB, vT, 8192, 2304, 768);

    attn_kernel<<<768, 256, 0, stream>>>(bufB, vT, bufA);

    gemm_bt_db<<<64 * (768 / 64), 256, 0, stream>>>(
        bufA, proj_wT, proj_b, x, bufC, 8192, 768, 768);

    layernorm_kernel<<<8192, 256, 0, stream>>>(bufC, n2g, n2b, bufA);

    gemm_bt<2><<<64 * (3072 / 128), 256, 0, stream>>>(
        bufA, fc1_wT, fc1_b, nullptr, bufB, nullptr, 8192, 3072, 768);

    gemm_bt_db<<<64 * (768 / 64), 256, 0, stream>>>(
        bufB, fc2_wT, fc2_b, bufC, out, 8192, 768, 3072);
}